// Round 3
// baseline (478.621 us; speedup 1.0000x reference)
//
#include <hip/hip_runtime.h>
#include <hip/hip_bf16.h>

#define N_FEAT 7
#define HIDDEN 128
#define N_CLASSES 2
#define N_GRAPHS 64

// ---------------------------------------------------------------- zero init
__global__ void k_zero(int* __restrict__ deg, float* __restrict__ gsum,
                       float* __restrict__ gcnt, int n) {
    int i = blockIdx.x * blockDim.x + threadIdx.x;
    if (i < n) deg[i] = 0;
    if (i < N_GRAPHS * HIDDEN) gsum[i] = 0.f;
    if (i < N_GRAPHS) gcnt[i] = 0.f;
}

// ---------------------------------------------------------------- degree count
__global__ void k_count(const int* __restrict__ dst, int* __restrict__ deg, int E) {
    int e = blockIdx.x * blockDim.x + threadIdx.x;
    if (e < E) atomicAdd(&deg[dst[e]], 1);
}

// ---------------------------------------------------------------- exclusive scan (single block)
// also writes cursor=start and dinv = rsqrt(deg+1)  (+1 = self loop)
__global__ __launch_bounds__(1024) void k_scan(const int* __restrict__ deg,
                                               int* __restrict__ start,
                                               int* __restrict__ cursor,
                                               float* __restrict__ dinv, int n) {
    __shared__ int s[1024];
    __shared__ int carry_s;
    int tid = threadIdx.x;
    if (tid == 0) carry_s = 0;
    __syncthreads();
    for (int base = 0; base < n; base += 1024) {
        int i = base + tid;
        int v = (i < n) ? deg[i] : 0;
        s[tid] = v;
        __syncthreads();
        // Hillis-Steele inclusive scan
        for (int off = 1; off < 1024; off <<= 1) {
            int t = (tid >= off) ? s[tid - off] : 0;
            __syncthreads();
            s[tid] += t;
            __syncthreads();
        }
        int carry = carry_s;
        if (i < n) {
            int ex = carry + s[tid] - v;   // exclusive
            start[i] = ex;
            cursor[i] = ex;
            dinv[i] = rsqrtf((float)(v + 1));
        }
        __syncthreads();
        if (tid == 1023) carry_s = carry + s[1023];
        __syncthreads();
    }
    if (tid == 0) start[n] = carry_s;
}

// ---------------------------------------------------------------- CSR fill
__global__ void k_fill(const int* __restrict__ src, const int* __restrict__ dst,
                       int* __restrict__ cursor, const float* __restrict__ dinv,
                       int* __restrict__ csr_src, float* __restrict__ csr_norm, int E) {
    int e = blockIdx.x * blockDim.x + threadIdx.x;
    if (e >= E) return;
    int s = src[e], d = dst[e];
    int pos = atomicAdd(&cursor[d], 1);
    csr_src[pos] = s;
    csr_norm[pos] = dinv[s] * dinv[d];
}

// ---------------------------------------------------------------- layer-1 transform: T = X[N,7] @ W1[7,128]
__global__ __launch_bounds__(256) void k_gemm7(const float* __restrict__ X,
                                               const float* __restrict__ W1,
                                               float* __restrict__ T, int n) {
    __shared__ float w[N_FEAT * HIDDEN];
    int tid = threadIdx.x;
    for (int i = tid; i < N_FEAT * HIDDEN; i += 256) w[i] = W1[i];
    __syncthreads();
    int row = blockIdx.x * 2 + (tid >> 7);
    int col = tid & 127;
    if (row >= n) return;
    float acc = 0.f;
#pragma unroll
    for (int k = 0; k < N_FEAT; ++k)
        acc += X[row * N_FEAT + k] * w[k * HIDDEN + col];
    T[(size_t)row * HIDDEN + col] = acc;
}

// ---------------------------------------------------------------- dense fp32 GEMM: C[n,128] = A[n,128] @ W[128,128]
// 128-row x 128-col block tile, 256 threads, 8x8 register micro-tile.
// A tile stored transposed in LDS (as[k][row], padded) so inner reads are ds_read_b128.
__global__ __launch_bounds__(256) void k_gemm128(const float* __restrict__ A,
                                                 const float* __restrict__ W,
                                                 float* __restrict__ C, int nrows) {
    __shared__ float as[16][136];   // [kk][row], pad 128->136 keeps 16B align, no bank conflict
    __shared__ float ws[16][128];   // [kk][col]
    int row0 = blockIdx.x * 128;
    int tid = threadIdx.x;
    int tr = tid >> 4;      // 0..15 -> rows tr*8..tr*8+7
    int tc = tid & 15;      // 0..15 -> cols tc*8..tc*8+7
    float acc[8][8] = {};
    for (int k0 = 0; k0 < 128; k0 += 16) {
        // stage A: 128 rows x 16 k  (thread: row=tid>>1, k-offset=(tid&1)*8)
        {
            int r = tid >> 1;
            int c = (tid & 1) << 3;
            if (row0 + r < nrows) {
                const float* ap = &A[(size_t)(row0 + r) * 128 + k0 + c];
                float4 v0 = *(const float4*)(ap);
                float4 v1 = *(const float4*)(ap + 4);
                as[c + 0][r] = v0.x; as[c + 1][r] = v0.y; as[c + 2][r] = v0.z; as[c + 3][r] = v0.w;
                as[c + 4][r] = v1.x; as[c + 5][r] = v1.y; as[c + 6][r] = v1.z; as[c + 7][r] = v1.w;
            } else {
#pragma unroll
                for (int j = 0; j < 8; ++j) as[c + j][r] = 0.f;
            }
        }
        // stage W: 16 k x 128 cols (thread: wr=tid>>4, wc=(tid&15)*8)
        {
            int wr = tid >> 4;
            int wc = (tid & 15) << 3;
            const float* wp = &W[(size_t)(k0 + wr) * 128 + wc];
            *(float4*)&ws[wr][wc] = *(const float4*)(wp);
            *(float4*)&ws[wr][wc + 4] = *(const float4*)(wp + 4);
        }
        __syncthreads();
#pragma unroll
        for (int kk = 0; kk < 16; ++kk) {
            float a[8], b[8];
            *(float4*)&a[0] = *(const float4*)&as[kk][tr * 8];
            *(float4*)&a[4] = *(const float4*)&as[kk][tr * 8 + 4];
            *(float4*)&b[0] = *(const float4*)&ws[kk][tc * 8];
            *(float4*)&b[4] = *(const float4*)&ws[kk][tc * 8 + 4];
#pragma unroll
            for (int i = 0; i < 8; ++i)
#pragma unroll
                for (int j = 0; j < 8; ++j)
                    acc[i][j] += a[i] * b[j];
        }
        __syncthreads();
    }
#pragma unroll
    for (int i = 0; i < 8; ++i) {
        int rr = row0 + tr * 8 + i;
        if (rr < nrows) {
            float* dstp = &C[(size_t)rr * 128 + tc * 8];
            *(float4*)(dstp)     = make_float4(acc[i][0], acc[i][1], acc[i][2], acc[i][3]);
            *(float4*)(dstp + 4) = make_float4(acc[i][4], acc[i][5], acc[i][6], acc[i][7]);
        }
    }
}

// ---------------------------------------------------------------- aggregation: H[i] = (sum_{e in CSR(i)} norm_e * T[src_e]) + dinv[i]^2 * T[i] + b ; optional relu
// 32 lanes per node, float4 per lane = one 512B coalesced row.
__global__ __launch_bounds__(256) void k_agg(const float* __restrict__ T, float* __restrict__ H,
                                             const int* __restrict__ start,
                                             const int* __restrict__ csr_src,
                                             const float* __restrict__ csr_norm,
                                             const float* __restrict__ dinv,
                                             const float* __restrict__ bias,
                                             int relu, int nnodes) {
    int g = (blockIdx.x * blockDim.x + threadIdx.x) >> 5;
    int lane = threadIdx.x & 31;
    if (g >= nnodes) return;
    float di = dinv[g];
    float self = di * di;
    float4 v = *(const float4*)&T[(size_t)g * 128 + lane * 4];
    float4 acc;
    acc.x = self * v.x; acc.y = self * v.y; acc.z = self * v.z; acc.w = self * v.w;
    int e0 = start[g], e1 = start[g + 1];
    for (int e = e0; e < e1; ++e) {
        int s = csr_src[e];
        float nrm = csr_norm[e];
        float4 u = *(const float4*)&T[(size_t)s * 128 + lane * 4];
        acc.x += nrm * u.x; acc.y += nrm * u.y; acc.z += nrm * u.z; acc.w += nrm * u.w;
    }
    float4 b = *(const float4*)&bias[lane * 4];
    acc.x += b.x; acc.y += b.y; acc.z += b.z; acc.w += b.w;
    if (relu) {
        acc.x = fmaxf(acc.x, 0.f); acc.y = fmaxf(acc.y, 0.f);
        acc.z = fmaxf(acc.z, 0.f); acc.w = fmaxf(acc.w, 0.f);
    }
    *(float4*)&H[(size_t)g * 128 + lane * 4] = acc;
}

// ---------------------------------------------------------------- pooling: batch is sorted -> register accumulate, flush per boundary
__global__ __launch_bounds__(128) void k_pool(const float* __restrict__ H,
                                              const int* __restrict__ batch,
                                              float* __restrict__ gsum,
                                              float* __restrict__ gcnt, int nnodes) {
    int d = threadIdx.x;                 // 0..127 (one dim per thread)
    int per = (nnodes + gridDim.x - 1) / gridDim.x;
    int n0 = blockIdx.x * per;
    int n1 = min(nnodes, n0 + per);
    if (n0 >= n1) return;
    int cur = batch[n0];
    float acc = 0.f;
    int cnt = 0;
    for (int n = n0; n < n1; ++n) {
        int b = batch[n];
        if (b != cur) {
            atomicAdd(&gsum[cur * HIDDEN + d], acc);
            if (d == 0) atomicAdd(&gcnt[cur], (float)cnt);
            acc = 0.f; cnt = 0; cur = b;
        }
        acc += H[(size_t)n * HIDDEN + d];
        cnt++;
    }
    atomicAdd(&gsum[cur * HIDDEN + d], acc);
    if (d == 0) atomicAdd(&gcnt[cur], (float)cnt);
}

// ---------------------------------------------------------------- final: out[64,2] = (gsum/cnt) @ Wl + bl
__global__ __launch_bounds__(128) void k_final(const float* __restrict__ gsum,
                                               const float* __restrict__ gcnt,
                                               const float* __restrict__ Wl,
                                               const float* __restrict__ bl,
                                               float* __restrict__ out) {
    int tid = threadIdx.x;               // 0..127
    int g = tid >> 1;
    int c = tid & 1;
    float inv = 1.0f / fmaxf(gcnt[g], 1.0f);
    float acc = 0.f;
#pragma unroll 8
    for (int k = 0; k < HIDDEN; ++k)
        acc += gsum[g * HIDDEN + k] * Wl[k * N_CLASSES + c];
    out[g * N_CLASSES + c] = acc * inv + bl[c];
}

// ================================================================ launch
extern "C" void kernel_launch(void* const* d_in, const int* in_sizes, int n_in,
                              void* d_out, int out_size, void* d_ws, size_t ws_size,
                              hipStream_t stream) {
    const float* x    = (const float*)d_in[0];
    const int*   ei   = (const int*)d_in[1];
    const int*   batch= (const int*)d_in[2];
    const float* W1   = (const float*)d_in[3];
    const float* b1   = (const float*)d_in[4];
    const float* W2   = (const float*)d_in[5];
    const float* b2   = (const float*)d_in[6];
    const float* W3   = (const float*)d_in[7];
    const float* b3   = (const float*)d_in[8];
    const float* Wl   = (const float*)d_in[9];
    const float* bl   = (const float*)d_in[10];
    float* out = (float*)d_out;

    const int N = in_sizes[0] / N_FEAT;        // 40000
    const int E = in_sizes[1] / 2;             // 640000
    const int* e_src = ei;
    const int* e_dst = ei + E;

    // workspace carve-out (256B aligned)
    char* ws = (char*)d_ws;
    auto carve = [&](size_t bytes) -> char* {
        char* p = ws;
        ws += (bytes + 255) & ~(size_t)255;
        return p;
    };
    float* T        = (float*)carve((size_t)N * HIDDEN * 4);
    float* H        = (float*)carve((size_t)N * HIDDEN * 4);
    int*   deg      = (int*)  carve((size_t)N * 4);
    int*   start    = (int*)  carve((size_t)(N + 1) * 4);
    int*   cursor   = (int*)  carve((size_t)N * 4);
    float* dinv     = (float*)carve((size_t)N * 4);
    int*   csr_src  = (int*)  carve((size_t)E * 4);
    float* csr_norm = (float*)carve((size_t)E * 4);
    float* gsum     = (float*)carve((size_t)N_GRAPHS * HIDDEN * 4);
    float* gcnt     = (float*)carve((size_t)N_GRAPHS * 4);
    if ((size_t)(ws - (char*)d_ws) > ws_size) return;   // workspace too small (shouldn't happen)

    // --- CSR build ---
    k_zero <<<(N + 255) / 256, 256, 0, stream>>>(deg, gsum, gcnt, N);
    k_count<<<(E + 255) / 256, 256, 0, stream>>>(e_dst, deg, E);
    k_scan <<<1, 1024, 0, stream>>>(deg, start, cursor, dinv, N);
    k_fill <<<(E + 255) / 256, 256, 0, stream>>>(e_src, e_dst, cursor, dinv, csr_src, csr_norm, E);

    const int aggBlocks  = (N * 32 + 255) / 256;          // 32 lanes/node
    const int gemmBlocks = (N + 127) / 128;

    // --- layer 1 ---
    k_gemm7<<<(N + 1) / 2, 256, 0, stream>>>(x, W1, T, N);
    k_agg  <<<aggBlocks, 256, 0, stream>>>(T, H, start, csr_src, csr_norm, dinv, b1, 1, N);
    // --- layer 2 ---
    k_gemm128<<<gemmBlocks, 256, 0, stream>>>(H, W2, T, N);
    k_agg    <<<aggBlocks, 256, 0, stream>>>(T, H, start, csr_src, csr_norm, dinv, b2, 1, N);
    // --- layer 3 (no relu) ---
    k_gemm128<<<gemmBlocks, 256, 0, stream>>>(H, W3, T, N);
    k_agg    <<<aggBlocks, 256, 0, stream>>>(T, H, start, csr_src, csr_norm, dinv, b3, 0, N);

    // --- pool + classifier ---
    k_pool <<<256, 128, 0, stream>>>(H, batch, gsum, gcnt, N);
    k_final<<<1, 128, 0, stream>>>(gsum, gcnt, Wl, bl, out);
}

// Round 4
// 387.706 us; speedup vs baseline: 1.2345x; 1.2345x over previous
//
#include <hip/hip_runtime.h>
#include <hip/hip_bf16.h>

#define N_FEAT 7
#define HIDDEN 128
#define N_CLASSES 2
#define N_GRAPHS 64
#define SCAN_TILE 1024

// ---------------------------------------------------------------- zero init
__global__ void k_zero(int* __restrict__ deg, float* __restrict__ gsum,
                       float* __restrict__ gcnt, int n) {
    int i = blockIdx.x * blockDim.x + threadIdx.x;
    if (i < n) deg[i] = 0;
    if (i < N_GRAPHS * HIDDEN) gsum[i] = 0.f;
    if (i < N_GRAPHS) gcnt[i] = 0.f;
}

// ---------------------------------------------------------------- degree count
__global__ void k_count(const int* __restrict__ dst, int* __restrict__ deg, int E) {
    int e = blockIdx.x * blockDim.x + threadIdx.x;
    if (e < E) atomicAdd(&deg[dst[e]], 1);
}

// ---------------------------------------------------------------- scan phase A: per-block sums
__global__ __launch_bounds__(1024) void k_scan_a(const int* __restrict__ deg,
                                                 int* __restrict__ bsum, int n) {
    __shared__ int s[SCAN_TILE];
    int tid = threadIdx.x;
    int i = blockIdx.x * SCAN_TILE + tid;
    s[tid] = (i < n) ? deg[i] : 0;
    __syncthreads();
#pragma unroll
    for (int off = 512; off > 0; off >>= 1) {
        if (tid < off) s[tid] += s[tid + off];
        __syncthreads();
    }
    if (tid == 0) bsum[blockIdx.x] = s[0];
}

// ---------------------------------------------------------------- scan phase B: scan of block sums (1 block; B <= 1024)
__global__ __launch_bounds__(1024) void k_scan_b(const int* __restrict__ bsum,
                                                 int* __restrict__ boff,
                                                 int* __restrict__ start, int B, int n) {
    __shared__ int s[SCAN_TILE];
    int tid = threadIdx.x;
    int v = (tid < B) ? bsum[tid] : 0;
    s[tid] = v;
    __syncthreads();
    for (int off = 1; off < SCAN_TILE; off <<= 1) {
        int t = (tid >= off) ? s[tid - off] : 0;
        __syncthreads();
        s[tid] += t;
        __syncthreads();
    }
    if (tid < B) boff[tid] = s[tid] - v;       // exclusive
    if (tid == B - 1) start[n] = s[tid];       // total = E
}

// ---------------------------------------------------------------- scan phase C: block-local scan + offset; write start/cursor/dinv
__global__ __launch_bounds__(1024) void k_scan_c(const int* __restrict__ deg,
                                                 const int* __restrict__ boff,
                                                 int* __restrict__ start,
                                                 int* __restrict__ cursor,
                                                 float* __restrict__ dinv, int n) {
    __shared__ int s[SCAN_TILE];
    int tid = threadIdx.x;
    int i = blockIdx.x * SCAN_TILE + tid;
    int v = (i < n) ? deg[i] : 0;
    s[tid] = v;
    __syncthreads();
    for (int off = 1; off < SCAN_TILE; off <<= 1) {
        int t = (tid >= off) ? s[tid - off] : 0;
        __syncthreads();
        s[tid] += t;
        __syncthreads();
    }
    if (i < n) {
        int ex = boff[blockIdx.x] + s[tid] - v;   // exclusive prefix
        start[i] = ex;
        cursor[i] = ex;
        dinv[i] = rsqrtf((float)(v + 1));
    }
}

// ---------------------------------------------------------------- CSR fill
__global__ void k_fill(const int* __restrict__ src, const int* __restrict__ dst,
                       int* __restrict__ cursor, const float* __restrict__ dinv,
                       int* __restrict__ csr_src, float* __restrict__ csr_norm, int E) {
    int e = blockIdx.x * blockDim.x + threadIdx.x;
    if (e >= E) return;
    int s = src[e], d = dst[e];
    int pos = atomicAdd(&cursor[d], 1);
    csr_src[pos] = s;
    csr_norm[pos] = dinv[s] * dinv[d];
}

// ---------------------------------------------------------------- layer-1 transform: T = X[N,7] @ W1[7,128]
__global__ __launch_bounds__(256) void k_gemm7(const float* __restrict__ X,
                                               const float* __restrict__ W1,
                                               float* __restrict__ T, int n) {
    __shared__ float w[N_FEAT * HIDDEN];
    int tid = threadIdx.x;
    for (int i = tid; i < N_FEAT * HIDDEN; i += 256) w[i] = W1[i];
    __syncthreads();
    int row = blockIdx.x * 2 + (tid >> 7);
    int col = tid & 127;
    if (row >= n) return;
    float acc = 0.f;
#pragma unroll
    for (int k = 0; k < N_FEAT; ++k)
        acc += X[row * N_FEAT + k] * w[k * HIDDEN + col];
    T[(size_t)row * HIDDEN + col] = acc;
}

// ---------------------------------------------------------------- dense fp32 GEMM: C[n,128] = A[n,128] @ W[128,128]
__global__ __launch_bounds__(256) void k_gemm128(const float* __restrict__ A,
                                                 const float* __restrict__ W,
                                                 float* __restrict__ C, int nrows) {
    __shared__ float as[16][136];   // [kk][row], padded
    __shared__ float ws[16][128];   // [kk][col]
    int row0 = blockIdx.x * 128;
    int tid = threadIdx.x;
    int tr = tid >> 4;      // 0..15 -> rows tr*8..tr*8+7
    int tc = tid & 15;      // 0..15 -> cols tc*8..tc*8+7
    float acc[8][8] = {};
    for (int k0 = 0; k0 < 128; k0 += 16) {
        {
            int r = tid >> 1;
            int c = (tid & 1) << 3;
            if (row0 + r < nrows) {
                const float* ap = &A[(size_t)(row0 + r) * 128 + k0 + c];
                float4 v0 = *(const float4*)(ap);
                float4 v1 = *(const float4*)(ap + 4);
                as[c + 0][r] = v0.x; as[c + 1][r] = v0.y; as[c + 2][r] = v0.z; as[c + 3][r] = v0.w;
                as[c + 4][r] = v1.x; as[c + 5][r] = v1.y; as[c + 6][r] = v1.z; as[c + 7][r] = v1.w;
            } else {
#pragma unroll
                for (int j = 0; j < 8; ++j) as[c + j][r] = 0.f;
            }
        }
        {
            int wr = tid >> 4;
            int wc = (tid & 15) << 3;
            const float* wp = &W[(size_t)(k0 + wr) * 128 + wc];
            *(float4*)&ws[wr][wc] = *(const float4*)(wp);
            *(float4*)&ws[wr][wc + 4] = *(const float4*)(wp + 4);
        }
        __syncthreads();
#pragma unroll
        for (int kk = 0; kk < 16; ++kk) {
            float a[8], b[8];
            *(float4*)&a[0] = *(const float4*)&as[kk][tr * 8];
            *(float4*)&a[4] = *(const float4*)&as[kk][tr * 8 + 4];
            *(float4*)&b[0] = *(const float4*)&ws[kk][tc * 8];
            *(float4*)&b[4] = *(const float4*)&ws[kk][tc * 8 + 4];
#pragma unroll
            for (int i = 0; i < 8; ++i)
#pragma unroll
                for (int j = 0; j < 8; ++j)
                    acc[i][j] += a[i] * b[j];
        }
        __syncthreads();
    }
#pragma unroll
    for (int i = 0; i < 8; ++i) {
        int rr = row0 + tr * 8 + i;
        if (rr < nrows) {
            float* dstp = &C[(size_t)rr * 128 + tc * 8];
            *(float4*)(dstp)     = make_float4(acc[i][0], acc[i][1], acc[i][2], acc[i][3]);
            *(float4*)(dstp + 4) = make_float4(acc[i][4], acc[i][5], acc[i][6], acc[i][7]);
        }
    }
}

// ---------------------------------------------------------------- aggregation (unroll-4 for MLP):
// H[i] = sum_e norm_e * T[src_e] + dinv[i]^2 * T[i] + b ; optional relu
__global__ __launch_bounds__(256) void k_agg(const float* __restrict__ T, float* __restrict__ H,
                                             const int* __restrict__ start,
                                             const int* __restrict__ csr_src,
                                             const float* __restrict__ csr_norm,
                                             const float* __restrict__ dinv,
                                             const float* __restrict__ bias,
                                             int relu, int nnodes) {
    int g = (blockIdx.x * blockDim.x + threadIdx.x) >> 5;
    int lane = threadIdx.x & 31;
    if (g >= nnodes) return;
    const size_t loff = (size_t)lane * 4;
    float di = dinv[g];
    float self = di * di;
    float4 v = *(const float4*)&T[(size_t)g * 128 + loff];
    float ax = self * v.x, ay = self * v.y, az = self * v.z, aw = self * v.w;
    int e0 = start[g], e1 = start[g + 1];
    int e = e0;
    for (; e + 4 <= e1; e += 4) {
        int s0 = csr_src[e + 0], s1 = csr_src[e + 1];
        int s2 = csr_src[e + 2], s3 = csr_src[e + 3];
        float w0 = csr_norm[e + 0], w1 = csr_norm[e + 1];
        float w2 = csr_norm[e + 2], w3 = csr_norm[e + 3];
        float4 u0 = *(const float4*)&T[(size_t)s0 * 128 + loff];
        float4 u1 = *(const float4*)&T[(size_t)s1 * 128 + loff];
        float4 u2 = *(const float4*)&T[(size_t)s2 * 128 + loff];
        float4 u3 = *(const float4*)&T[(size_t)s3 * 128 + loff];
        ax += w0 * u0.x; ay += w0 * u0.y; az += w0 * u0.z; aw += w0 * u0.w;
        ax += w1 * u1.x; ay += w1 * u1.y; az += w1 * u1.z; aw += w1 * u1.w;
        ax += w2 * u2.x; ay += w2 * u2.y; az += w2 * u2.z; aw += w2 * u2.w;
        ax += w3 * u3.x; ay += w3 * u3.y; az += w3 * u3.z; aw += w3 * u3.w;
    }
    for (; e < e1; ++e) {
        int s = csr_src[e];
        float w = csr_norm[e];
        float4 u = *(const float4*)&T[(size_t)s * 128 + loff];
        ax += w * u.x; ay += w * u.y; az += w * u.z; aw += w * u.w;
    }
    float4 b = *(const float4*)&bias[loff];
    ax += b.x; ay += b.y; az += b.z; aw += b.w;
    if (relu) {
        ax = fmaxf(ax, 0.f); ay = fmaxf(ay, 0.f);
        az = fmaxf(az, 0.f); aw = fmaxf(aw, 0.f);
    }
    *(float4*)&H[(size_t)g * 128 + loff] = make_float4(ax, ay, az, aw);
}

// ---------------------------------------------------------------- pooling: batch sorted -> register accumulate, flush per boundary
__global__ __launch_bounds__(128) void k_pool(const float* __restrict__ H,
                                              const int* __restrict__ batch,
                                              float* __restrict__ gsum,
                                              float* __restrict__ gcnt, int nnodes) {
    int d = threadIdx.x;                 // 0..127
    int per = (nnodes + gridDim.x - 1) / gridDim.x;
    int n0 = blockIdx.x * per;
    int n1 = min(nnodes, n0 + per);
    if (n0 >= n1) return;
    int cur = batch[n0];
    float acc = 0.f;
    int cnt = 0;
    for (int n = n0; n < n1; ++n) {
        int b = batch[n];
        if (b != cur) {
            atomicAdd(&gsum[cur * HIDDEN + d], acc);
            if (d == 0) atomicAdd(&gcnt[cur], (float)cnt);
            acc = 0.f; cnt = 0; cur = b;
        }
        acc += H[(size_t)n * HIDDEN + d];
        cnt++;
    }
    atomicAdd(&gsum[cur * HIDDEN + d], acc);
    if (d == 0) atomicAdd(&gcnt[cur], (float)cnt);
}

// ---------------------------------------------------------------- final: out[64,2] = (gsum/cnt) @ Wl + bl
__global__ __launch_bounds__(128) void k_final(const float* __restrict__ gsum,
                                               const float* __restrict__ gcnt,
                                               const float* __restrict__ Wl,
                                               const float* __restrict__ bl,
                                               float* __restrict__ out) {
    int tid = threadIdx.x;               // 0..127
    int g = tid >> 1;
    int c = tid & 1;
    float inv = 1.0f / fmaxf(gcnt[g], 1.0f);
    float acc = 0.f;
#pragma unroll 8
    for (int k = 0; k < HIDDEN; ++k)
        acc += gsum[g * HIDDEN + k] * Wl[k * N_CLASSES + c];
    out[g * N_CLASSES + c] = acc * inv + bl[c];
}

// ================================================================ launch
extern "C" void kernel_launch(void* const* d_in, const int* in_sizes, int n_in,
                              void* d_out, int out_size, void* d_ws, size_t ws_size,
                              hipStream_t stream) {
    const float* x    = (const float*)d_in[0];
    const int*   ei   = (const int*)d_in[1];
    const int*   batch= (const int*)d_in[2];
    const float* W1   = (const float*)d_in[3];
    const float* b1   = (const float*)d_in[4];
    const float* W2   = (const float*)d_in[5];
    const float* b2   = (const float*)d_in[6];
    const float* W3   = (const float*)d_in[7];
    const float* b3   = (const float*)d_in[8];
    const float* Wl   = (const float*)d_in[9];
    const float* bl   = (const float*)d_in[10];
    float* out = (float*)d_out;

    const int N = in_sizes[0] / N_FEAT;        // 40000
    const int E = in_sizes[1] / 2;             // 640000
    const int* e_src = ei;
    const int* e_dst = ei + E;
    const int B = (N + SCAN_TILE - 1) / SCAN_TILE;   // 40 scan blocks (<=1024 required)

    // workspace carve-out (256B aligned)
    char* ws = (char*)d_ws;
    auto carve = [&](size_t bytes) -> char* {
        char* p = ws;
        ws += (bytes + 255) & ~(size_t)255;
        return p;
    };
    float* T        = (float*)carve((size_t)N * HIDDEN * 4);
    float* H        = (float*)carve((size_t)N * HIDDEN * 4);
    int*   deg      = (int*)  carve((size_t)N * 4);
    int*   start    = (int*)  carve((size_t)(N + 1) * 4);
    int*   cursor   = (int*)  carve((size_t)N * 4);
    float* dinv     = (float*)carve((size_t)N * 4);
    int*   csr_src  = (int*)  carve((size_t)E * 4);
    float* csr_norm = (float*)carve((size_t)E * 4);
    float* gsum     = (float*)carve((size_t)N_GRAPHS * HIDDEN * 4);
    float* gcnt     = (float*)carve((size_t)N_GRAPHS * 4);
    int*   bsum     = (int*)  carve((size_t)B * 4);
    int*   boff     = (int*)  carve((size_t)B * 4);
    if ((size_t)(ws - (char*)d_ws) > ws_size) return;

    // --- CSR build ---
    k_zero  <<<(N + 255) / 256, 256, 0, stream>>>(deg, gsum, gcnt, N);
    k_count <<<(E + 255) / 256, 256, 0, stream>>>(e_dst, deg, E);
    k_scan_a<<<B, 1024, 0, stream>>>(deg, bsum, N);
    k_scan_b<<<1, 1024, 0, stream>>>(bsum, boff, start, B, N);
    k_scan_c<<<B, 1024, 0, stream>>>(deg, boff, start, cursor, dinv, N);
    k_fill  <<<(E + 255) / 256, 256, 0, stream>>>(e_src, e_dst, cursor, dinv, csr_src, csr_norm, E);

    const int aggBlocks  = (N * 32 + 255) / 256;          // 32 lanes/node
    const int gemmBlocks = (N + 127) / 128;

    // --- layer 1 ---
    k_gemm7<<<(N + 1) / 2, 256, 0, stream>>>(x, W1, T, N);
    k_agg  <<<aggBlocks, 256, 0, stream>>>(T, H, start, csr_src, csr_norm, dinv, b1, 1, N);
    // --- layer 2 ---
    k_gemm128<<<gemmBlocks, 256, 0, stream>>>(H, W2, T, N);
    k_agg    <<<aggBlocks, 256, 0, stream>>>(T, H, start, csr_src, csr_norm, dinv, b2, 1, N);
    // --- layer 3 (no relu) ---
    k_gemm128<<<gemmBlocks, 256, 0, stream>>>(H, W3, T, N);
    k_agg    <<<aggBlocks, 256, 0, stream>>>(T, H, start, csr_src, csr_norm, dinv, b3, 0, N);

    // --- pool + classifier ---
    k_pool <<<256, 128, 0, stream>>>(H, batch, gsum, gcnt, N);
    k_final<<<1, 128, 0, stream>>>(gsum, gcnt, Wl, bl, out);
}

// Round 5
// 376.967 us; speedup vs baseline: 1.2697x; 1.0285x over previous
//
#include <hip/hip_runtime.h>
#include <hip/hip_bf16.h>

#define N_FEAT 7
#define HIDDEN 128
#define N_CLASSES 2
#define N_GRAPHS 64
#define SCAN_TILE 1024

// ---------------------------------------------------------------- zero init
__global__ void k_zero(int* __restrict__ deg, float* __restrict__ gsum,
                       float* __restrict__ gcnt, int n) {
    int i = blockIdx.x * blockDim.x + threadIdx.x;
    if (i < n) deg[i] = 0;
    if (i < N_GRAPHS * HIDDEN) gsum[i] = 0.f;
    if (i < N_GRAPHS) gcnt[i] = 0.f;
}

// ---------------------------------------------------------------- degree count (4 edges/thread)
__global__ void k_count(const int* __restrict__ dst, int* __restrict__ deg, int E) {
    int e4 = (blockIdx.x * blockDim.x + threadIdx.x) << 2;
    if (e4 + 4 <= E) {
        int4 d = *(const int4*)&dst[e4];
        atomicAdd(&deg[d.x], 1);
        atomicAdd(&deg[d.y], 1);
        atomicAdd(&deg[d.z], 1);
        atomicAdd(&deg[d.w], 1);
    } else {
        for (int e = e4; e < E; ++e) atomicAdd(&deg[dst[e]], 1);
    }
}

// ---------------------------------------------------------------- scan phase A: per-block sums
__global__ __launch_bounds__(1024) void k_scan_a(const int* __restrict__ deg,
                                                 int* __restrict__ bsum, int n) {
    __shared__ int s[SCAN_TILE];
    int tid = threadIdx.x;
    int i = blockIdx.x * SCAN_TILE + tid;
    s[tid] = (i < n) ? deg[i] : 0;
    __syncthreads();
#pragma unroll
    for (int off = 512; off > 0; off >>= 1) {
        if (tid < off) s[tid] += s[tid + off];
        __syncthreads();
    }
    if (tid == 0) bsum[blockIdx.x] = s[0];
}

// ---------------------------------------------------------------- scan phase B: scan of block sums (1 block; B <= 1024)
__global__ __launch_bounds__(1024) void k_scan_b(const int* __restrict__ bsum,
                                                 int* __restrict__ boff,
                                                 int* __restrict__ start, int B, int n) {
    __shared__ int s[SCAN_TILE];
    int tid = threadIdx.x;
    int v = (tid < B) ? bsum[tid] : 0;
    s[tid] = v;
    __syncthreads();
    for (int off = 1; off < SCAN_TILE; off <<= 1) {
        int t = (tid >= off) ? s[tid - off] : 0;
        __syncthreads();
        s[tid] += t;
        __syncthreads();
    }
    if (tid < B) boff[tid] = s[tid] - v;       // exclusive
    if (tid == B - 1) start[n] = s[tid];       // total = E
}

// ---------------------------------------------------------------- scan phase C: block-local scan + offset; write start/cursor/dinv
__global__ __launch_bounds__(1024) void k_scan_c(const int* __restrict__ deg,
                                                 const int* __restrict__ boff,
                                                 int* __restrict__ start,
                                                 int* __restrict__ cursor,
                                                 float* __restrict__ dinv, int n) {
    __shared__ int s[SCAN_TILE];
    int tid = threadIdx.x;
    int i = blockIdx.x * SCAN_TILE + tid;
    int v = (i < n) ? deg[i] : 0;
    s[tid] = v;
    __syncthreads();
    for (int off = 1; off < SCAN_TILE; off <<= 1) {
        int t = (tid >= off) ? s[tid - off] : 0;
        __syncthreads();
        s[tid] += t;
        __syncthreads();
    }
    if (i < n) {
        int ex = boff[blockIdx.x] + s[tid] - v;   // exclusive prefix
        start[i] = ex;
        cursor[i] = ex;
        dinv[i] = rsqrtf((float)(v + 1));
    }
}

// ---------------------------------------------------------------- CSR fill: src index ONLY (norm computed in agg)
// 4 edges/thread; one scattered 4B store per edge.
__global__ void k_fill(const int* __restrict__ src, const int* __restrict__ dst,
                       int* __restrict__ cursor, int* __restrict__ csr_src, int E) {
    int e4 = (blockIdx.x * blockDim.x + threadIdx.x) << 2;
    if (e4 + 4 <= E) {
        int4 s = *(const int4*)&src[e4];
        int4 d = *(const int4*)&dst[e4];
        csr_src[atomicAdd(&cursor[d.x], 1)] = s.x;
        csr_src[atomicAdd(&cursor[d.y], 1)] = s.y;
        csr_src[atomicAdd(&cursor[d.z], 1)] = s.z;
        csr_src[atomicAdd(&cursor[d.w], 1)] = s.w;
    } else {
        for (int e = e4; e < E; ++e)
            csr_src[atomicAdd(&cursor[dst[e]], 1)] = src[e];
    }
}

// ---------------------------------------------------------------- layer-1 transform: T = X[N,7] @ W1[7,128]
__global__ __launch_bounds__(256) void k_gemm7(const float* __restrict__ X,
                                               const float* __restrict__ W1,
                                               float* __restrict__ T, int n) {
    __shared__ float w[N_FEAT * HIDDEN];
    int tid = threadIdx.x;
    for (int i = tid; i < N_FEAT * HIDDEN; i += 256) w[i] = W1[i];
    __syncthreads();
    int row = blockIdx.x * 2 + (tid >> 7);
    int col = tid & 127;
    if (row >= n) return;
    float acc = 0.f;
#pragma unroll
    for (int k = 0; k < N_FEAT; ++k)
        acc += X[row * N_FEAT + k] * w[k * HIDDEN + col];
    T[(size_t)row * HIDDEN + col] = acc;
}

// ---------------------------------------------------------------- dense fp32 GEMM: C[n,128] = A[n,128] @ W[128,128]
__global__ __launch_bounds__(256) void k_gemm128(const float* __restrict__ A,
                                                 const float* __restrict__ W,
                                                 float* __restrict__ C, int nrows) {
    __shared__ float as[16][136];   // [kk][row], padded
    __shared__ float ws[16][128];   // [kk][col]
    int row0 = blockIdx.x * 128;
    int tid = threadIdx.x;
    int tr = tid >> 4;      // 0..15 -> rows tr*8..tr*8+7
    int tc = tid & 15;      // 0..15 -> cols tc*8..tc*8+7
    float acc[8][8] = {};
    for (int k0 = 0; k0 < 128; k0 += 16) {
        {
            int r = tid >> 1;
            int c = (tid & 1) << 3;
            if (row0 + r < nrows) {
                const float* ap = &A[(size_t)(row0 + r) * 128 + k0 + c];
                float4 v0 = *(const float4*)(ap);
                float4 v1 = *(const float4*)(ap + 4);
                as[c + 0][r] = v0.x; as[c + 1][r] = v0.y; as[c + 2][r] = v0.z; as[c + 3][r] = v0.w;
                as[c + 4][r] = v1.x; as[c + 5][r] = v1.y; as[c + 6][r] = v1.z; as[c + 7][r] = v1.w;
            } else {
#pragma unroll
                for (int j = 0; j < 8; ++j) as[c + j][r] = 0.f;
            }
        }
        {
            int wr = tid >> 4;
            int wc = (tid & 15) << 3;
            const float* wp = &W[(size_t)(k0 + wr) * 128 + wc];
            *(float4*)&ws[wr][wc] = *(const float4*)(wp);
            *(float4*)&ws[wr][wc + 4] = *(const float4*)(wp + 4);
        }
        __syncthreads();
#pragma unroll
        for (int kk = 0; kk < 16; ++kk) {
            float a[8], b[8];
            *(float4*)&a[0] = *(const float4*)&as[kk][tr * 8];
            *(float4*)&a[4] = *(const float4*)&as[kk][tr * 8 + 4];
            *(float4*)&b[0] = *(const float4*)&ws[kk][tc * 8];
            *(float4*)&b[4] = *(const float4*)&ws[kk][tc * 8 + 4];
#pragma unroll
            for (int i = 0; i < 8; ++i)
#pragma unroll
                for (int j = 0; j < 8; ++j)
                    acc[i][j] += a[i] * b[j];
        }
        __syncthreads();
    }
#pragma unroll
    for (int i = 0; i < 8; ++i) {
        int rr = row0 + tr * 8 + i;
        if (rr < nrows) {
            float* dstp = &C[(size_t)rr * 128 + tc * 8];
            *(float4*)(dstp)     = make_float4(acc[i][0], acc[i][1], acc[i][2], acc[i][3]);
            *(float4*)(dstp + 4) = make_float4(acc[i][4], acc[i][5], acc[i][6], acc[i][7]);
        }
    }
}

// ---------------------------------------------------------------- aggregation (unroll-8 MLP, norm computed on the fly):
// H[i] = sum_e dinv[src_e]*dinv[i] * T[src_e] + dinv[i]^2 * T[i] + b ; optional relu
__global__ __launch_bounds__(256) void k_agg(const float* __restrict__ T, float* __restrict__ H,
                                             const int* __restrict__ start,
                                             const int* __restrict__ csr_src,
                                             const float* __restrict__ dinv,
                                             const float* __restrict__ bias,
                                             int relu, int nnodes) {
    int g = (blockIdx.x * blockDim.x + threadIdx.x) >> 5;
    int lane = threadIdx.x & 31;
    if (g >= nnodes) return;
    const size_t loff = (size_t)lane * 4;
    float di = dinv[g];
    float4 v = *(const float4*)&T[(size_t)g * 128 + loff];
    float self = di * di;
    float ax = self * v.x, ay = self * v.y, az = self * v.z, aw = self * v.w;
    int e0 = start[g], e1 = start[g + 1];
    int e = e0;
    for (; e + 8 <= e1; e += 8) {
        int   s[8];
        float w[8];
        float4 u[8];
#pragma unroll
        for (int j = 0; j < 8; ++j) s[j] = csr_src[e + j];
#pragma unroll
        for (int j = 0; j < 8; ++j) u[j] = *(const float4*)&T[(size_t)s[j] * 128 + loff];
#pragma unroll
        for (int j = 0; j < 8; ++j) w[j] = dinv[s[j]] * di;
#pragma unroll
        for (int j = 0; j < 8; ++j) {
            ax += w[j] * u[j].x; ay += w[j] * u[j].y;
            az += w[j] * u[j].z; aw += w[j] * u[j].w;
        }
    }
    if (e + 4 <= e1) {
        int   s[4];
        float w[4];
        float4 u[4];
#pragma unroll
        for (int j = 0; j < 4; ++j) s[j] = csr_src[e + j];
#pragma unroll
        for (int j = 0; j < 4; ++j) u[j] = *(const float4*)&T[(size_t)s[j] * 128 + loff];
#pragma unroll
        for (int j = 0; j < 4; ++j) w[j] = dinv[s[j]] * di;
#pragma unroll
        for (int j = 0; j < 4; ++j) {
            ax += w[j] * u[j].x; ay += w[j] * u[j].y;
            az += w[j] * u[j].z; aw += w[j] * u[j].w;
        }
        e += 4;
    }
    for (; e < e1; ++e) {
        int s = csr_src[e];
        float w = dinv[s] * di;
        float4 u = *(const float4*)&T[(size_t)s * 128 + loff];
        ax += w * u.x; ay += w * u.y; az += w * u.z; aw += w * u.w;
    }
    float4 b = *(const float4*)&bias[loff];
    ax += b.x; ay += b.y; az += b.z; aw += b.w;
    if (relu) {
        ax = fmaxf(ax, 0.f); ay = fmaxf(ay, 0.f);
        az = fmaxf(az, 0.f); aw = fmaxf(aw, 0.f);
    }
    *(float4*)&H[(size_t)g * 128 + loff] = make_float4(ax, ay, az, aw);
}

// ---------------------------------------------------------------- pooling: batch sorted -> register accumulate, flush per boundary
__global__ __launch_bounds__(128) void k_pool(const float* __restrict__ H,
                                              const int* __restrict__ batch,
                                              float* __restrict__ gsum,
                                              float* __restrict__ gcnt, int nnodes) {
    int d = threadIdx.x;                 // 0..127
    int per = (nnodes + gridDim.x - 1) / gridDim.x;
    int n0 = blockIdx.x * per;
    int n1 = min(nnodes, n0 + per);
    if (n0 >= n1) return;
    int cur = batch[n0];
    float acc = 0.f;
    int cnt = 0;
    for (int n = n0; n < n1; ++n) {
        int b = batch[n];
        if (b != cur) {
            atomicAdd(&gsum[cur * HIDDEN + d], acc);
            if (d == 0) atomicAdd(&gcnt[cur], (float)cnt);
            acc = 0.f; cnt = 0; cur = b;
        }
        acc += H[(size_t)n * HIDDEN + d];
        cnt++;
    }
    atomicAdd(&gsum[cur * HIDDEN + d], acc);
    if (d == 0) atomicAdd(&gcnt[cur], (float)cnt);
}

// ---------------------------------------------------------------- final: out[64,2] = (gsum/cnt) @ Wl + bl
__global__ __launch_bounds__(128) void k_final(const float* __restrict__ gsum,
                                               const float* __restrict__ gcnt,
                                               const float* __restrict__ Wl,
                                               const float* __restrict__ bl,
                                               float* __restrict__ out) {
    int tid = threadIdx.x;               // 0..127
    int g = tid >> 1;
    int c = tid & 1;
    float inv = 1.0f / fmaxf(gcnt[g], 1.0f);
    float acc = 0.f;
#pragma unroll 8
    for (int k = 0; k < HIDDEN; ++k)
        acc += gsum[g * HIDDEN + k] * Wl[k * N_CLASSES + c];
    out[g * N_CLASSES + c] = acc * inv + bl[c];
}

// ================================================================ launch
extern "C" void kernel_launch(void* const* d_in, const int* in_sizes, int n_in,
                              void* d_out, int out_size, void* d_ws, size_t ws_size,
                              hipStream_t stream) {
    const float* x    = (const float*)d_in[0];
    const int*   ei   = (const int*)d_in[1];
    const int*   batch= (const int*)d_in[2];
    const float* W1   = (const float*)d_in[3];
    const float* b1   = (const float*)d_in[4];
    const float* W2   = (const float*)d_in[5];
    const float* b2   = (const float*)d_in[6];
    const float* W3   = (const float*)d_in[7];
    const float* b3   = (const float*)d_in[8];
    const float* Wl   = (const float*)d_in[9];
    const float* bl   = (const float*)d_in[10];
    float* out = (float*)d_out;

    const int N = in_sizes[0] / N_FEAT;        // 40000
    const int E = in_sizes[1] / 2;             // 640000
    const int* e_src = ei;
    const int* e_dst = ei + E;
    const int B = (N + SCAN_TILE - 1) / SCAN_TILE;   // 40 scan blocks (<=1024 required)

    // workspace carve-out (256B aligned)
    char* ws = (char*)d_ws;
    auto carve = [&](size_t bytes) -> char* {
        char* p = ws;
        ws += (bytes + 255) & ~(size_t)255;
        return p;
    };
    float* T        = (float*)carve((size_t)N * HIDDEN * 4);
    float* H        = (float*)carve((size_t)N * HIDDEN * 4);
    int*   deg      = (int*)  carve((size_t)N * 4);
    int*   start    = (int*)  carve((size_t)(N + 1) * 4);
    int*   cursor   = (int*)  carve((size_t)N * 4);
    float* dinv     = (float*)carve((size_t)N * 4);
    int*   csr_src  = (int*)  carve((size_t)E * 4);
    float* gsum     = (float*)carve((size_t)N_GRAPHS * HIDDEN * 4);
    float* gcnt     = (float*)carve((size_t)N_GRAPHS * 4);
    int*   bsum     = (int*)  carve((size_t)B * 4);
    int*   boff     = (int*)  carve((size_t)B * 4);
    if ((size_t)(ws - (char*)d_ws) > ws_size) return;

    // --- CSR build ---
    k_zero  <<<(N + 255) / 256, 256, 0, stream>>>(deg, gsum, gcnt, N);
    k_count <<<(E / 4 + 255) / 256, 256, 0, stream>>>(e_dst, deg, E);
    k_scan_a<<<B, 1024, 0, stream>>>(deg, bsum, N);
    k_scan_b<<<1, 1024, 0, stream>>>(bsum, boff, start, B, N);
    k_scan_c<<<B, 1024, 0, stream>>>(deg, boff, start, cursor, dinv, N);
    k_fill  <<<(E / 4 + 255) / 256, 256, 0, stream>>>(e_src, e_dst, cursor, csr_src, E);

    const int aggBlocks  = (N * 32 + 255) / 256;          // 32 lanes/node
    const int gemmBlocks = (N + 127) / 128;

    // --- layer 1 ---
    k_gemm7<<<(N + 1) / 2, 256, 0, stream>>>(x, W1, T, N);
    k_agg  <<<aggBlocks, 256, 0, stream>>>(T, H, start, csr_src, dinv, b1, 1, N);
    // --- layer 2 ---
    k_gemm128<<<gemmBlocks, 256, 0, stream>>>(H, W2, T, N);
    k_agg    <<<aggBlocks, 256, 0, stream>>>(T, H, start, csr_src, dinv, b2, 1, N);
    // --- layer 3 (no relu) ---
    k_gemm128<<<gemmBlocks, 256, 0, stream>>>(H, W3, T, N);
    k_agg    <<<aggBlocks, 256, 0, stream>>>(T, H, start, csr_src, dinv, b3, 0, N);

    // --- pool + classifier ---
    k_pool <<<256, 128, 0, stream>>>(H, batch, gsum, gcnt, N);
    k_final<<<1, 128, 0, stream>>>(gsum, gcnt, Wl, bl, out);
}

// Round 6
// 335.485 us; speedup vs baseline: 1.4267x; 1.1236x over previous
//
#include <hip/hip_runtime.h>
#include <hip/hip_bf16.h>

#define N_FEAT 7
#define HIDDEN 128
#define N_CLASSES 2
#define N_GRAPHS 64
#define SCAN_TILE 1024

// ---------------------------------------------------------------- zero init
__global__ void k_zero(int* __restrict__ deg, float* __restrict__ gsum,
                       float* __restrict__ gcnt, int n) {
    int i = blockIdx.x * blockDim.x + threadIdx.x;
    if (i < n) deg[i] = 0;
    if (i < N_GRAPHS * HIDDEN) gsum[i] = 0.f;
    if (i < N_GRAPHS) gcnt[i] = 0.f;
}

// ---------------------------------------------------------------- degree count (4 edges/thread)
__global__ void k_count(const int* __restrict__ dst, int* __restrict__ deg, int E) {
    int e4 = (blockIdx.x * blockDim.x + threadIdx.x) << 2;
    if (e4 + 4 <= E) {
        int4 d = *(const int4*)&dst[e4];
        atomicAdd(&deg[d.x], 1);
        atomicAdd(&deg[d.y], 1);
        atomicAdd(&deg[d.z], 1);
        atomicAdd(&deg[d.w], 1);
    } else {
        for (int e = e4; e < E; ++e) atomicAdd(&deg[dst[e]], 1);
    }
}

// ---------------------------------------------------------------- scan phase A: per-block sums
__global__ __launch_bounds__(1024) void k_scan_a(const int* __restrict__ deg,
                                                 int* __restrict__ bsum, int n) {
    __shared__ int s[SCAN_TILE];
    int tid = threadIdx.x;
    int i = blockIdx.x * SCAN_TILE + tid;
    s[tid] = (i < n) ? deg[i] : 0;
    __syncthreads();
#pragma unroll
    for (int off = 512; off > 0; off >>= 1) {
        if (tid < off) s[tid] += s[tid + off];
        __syncthreads();
    }
    if (tid == 0) bsum[blockIdx.x] = s[0];
}

// ---------------------------------------------------------------- scan phase B: scan of block sums (1 block; B <= 1024)
__global__ __launch_bounds__(1024) void k_scan_b(const int* __restrict__ bsum,
                                                 int* __restrict__ boff,
                                                 int* __restrict__ start, int B, int n) {
    __shared__ int s[SCAN_TILE];
    int tid = threadIdx.x;
    int v = (tid < B) ? bsum[tid] : 0;
    s[tid] = v;
    __syncthreads();
    for (int off = 1; off < SCAN_TILE; off <<= 1) {
        int t = (tid >= off) ? s[tid - off] : 0;
        __syncthreads();
        s[tid] += t;
        __syncthreads();
    }
    if (tid < B) boff[tid] = s[tid] - v;       // exclusive
    if (tid == B - 1) start[n] = s[tid];       // total = E
}

// ---------------------------------------------------------------- scan phase C: block-local scan + offset; write start/cursor/dinv
__global__ __launch_bounds__(1024) void k_scan_c(const int* __restrict__ deg,
                                                 const int* __restrict__ boff,
                                                 int* __restrict__ start,
                                                 int* __restrict__ cursor,
                                                 float* __restrict__ dinv, int n) {
    __shared__ int s[SCAN_TILE];
    int tid = threadIdx.x;
    int i = blockIdx.x * SCAN_TILE + tid;
    int v = (i < n) ? deg[i] : 0;
    s[tid] = v;
    __syncthreads();
    for (int off = 1; off < SCAN_TILE; off <<= 1) {
        int t = (tid >= off) ? s[tid - off] : 0;
        __syncthreads();
        s[tid] += t;
        __syncthreads();
    }
    if (i < n) {
        int ex = boff[blockIdx.x] + s[tid] - v;   // exclusive prefix
        start[i] = ex;
        cursor[i] = ex;
        dinv[i] = rsqrtf((float)(v + 1));
    }
}

// ---------------------------------------------------------------- CSR fill: src index only (norm computed in agg)
__global__ void k_fill(const int* __restrict__ src, const int* __restrict__ dst,
                       int* __restrict__ cursor, int* __restrict__ csr_src, int E) {
    int e4 = (blockIdx.x * blockDim.x + threadIdx.x) << 2;
    if (e4 + 4 <= E) {
        int4 s = *(const int4*)&src[e4];
        int4 d = *(const int4*)&dst[e4];
        csr_src[atomicAdd(&cursor[d.x], 1)] = s.x;
        csr_src[atomicAdd(&cursor[d.y], 1)] = s.y;
        csr_src[atomicAdd(&cursor[d.z], 1)] = s.z;
        csr_src[atomicAdd(&cursor[d.w], 1)] = s.w;
    } else {
        for (int e = e4; e < E; ++e)
            csr_src[atomicAdd(&cursor[dst[e]], 1)] = src[e];
    }
}

// ---------------------------------------------------------------- layer-1 transform: T = X[N,7] @ W1[7,128]
__global__ __launch_bounds__(256) void k_gemm7(const float* __restrict__ X,
                                               const float* __restrict__ W1,
                                               float* __restrict__ T, int n) {
    __shared__ float w[N_FEAT * HIDDEN];
    int tid = threadIdx.x;
    for (int i = tid; i < N_FEAT * HIDDEN; i += 256) w[i] = W1[i];
    __syncthreads();
    int row = blockIdx.x * 2 + (tid >> 7);
    int col = tid & 127;
    if (row >= n) return;
    float acc = 0.f;
#pragma unroll
    for (int k = 0; k < N_FEAT; ++k)
        acc += X[row * N_FEAT + k] * w[k * HIDDEN + col];
    T[(size_t)row * HIDDEN + col] = acc;
}

// ---------------------------------------------------------------- dense fp32 GEMM: C[n,128] = A[n,128] @ W[128,128]
// 64-row blocks (grid 625), 256 threads, 4x8 micro-tile with SPLIT columns
// (cols tc*4..+3 and 64+tc*4..+3) so every LDS access is 16B-stride => 2-way
// bank aliasing (free). A tile transposed in LDS.
__global__ __launch_bounds__(256) void k_gemm128(const float* __restrict__ A,
                                                 const float* __restrict__ W,
                                                 float* __restrict__ C, int nrows) {
    __shared__ float as[16][68];    // [k][row], padded 64->68
    __shared__ float ws[16][132];   // [k][col], padded 128->132
    int row0 = blockIdx.x * 64;
    int tid = threadIdx.x;
    int tr = tid >> 4;      // 0..15 -> rows tr*4..tr*4+3
    int tc = tid & 15;      // cols tc*4..+3 and 64+tc*4..+3
    float acc[4][8] = {};
    for (int k0 = 0; k0 < 128; k0 += 16) {
        // stage A: 64 rows x 16 k ; thread: row=tid>>2, k-off=(tid&3)*4
        {
            int r = tid >> 2;
            int ko = (tid & 3) << 2;
            float4 av = make_float4(0.f, 0.f, 0.f, 0.f);
            if (row0 + r < nrows)
                av = *(const float4*)&A[(size_t)(row0 + r) * 128 + k0 + ko];
            as[ko + 0][r] = av.x; as[ko + 1][r] = av.y;
            as[ko + 2][r] = av.z; as[ko + 3][r] = av.w;
        }
        // stage W: 16 k x 128 cols; thread: k=tid>>4, cols (tid&15)*4 and +64
        {
            int wk = tid >> 4;
            int wc = (tid & 15) << 2;
            const float* wp = &W[(size_t)(k0 + wk) * 128 + wc];
            *(float4*)&ws[wk][wc]      = *(const float4*)(wp);
            *(float4*)&ws[wk][wc + 64] = *(const float4*)(wp + 64);
        }
        __syncthreads();
#pragma unroll
        for (int kk = 0; kk < 16; ++kk) {
            float a[4], b[8];
            *(float4*)&a[0] = *(const float4*)&as[kk][tr * 4];
            *(float4*)&b[0] = *(const float4*)&ws[kk][tc * 4];
            *(float4*)&b[4] = *(const float4*)&ws[kk][64 + tc * 4];
#pragma unroll
            for (int i = 0; i < 4; ++i)
#pragma unroll
                for (int j = 0; j < 8; ++j)
                    acc[i][j] += a[i] * b[j];
        }
        __syncthreads();
    }
#pragma unroll
    for (int i = 0; i < 4; ++i) {
        int rr = row0 + tr * 4 + i;
        if (rr < nrows) {
            float* dstp = &C[(size_t)rr * 128];
            *(float4*)(dstp + tc * 4)      = make_float4(acc[i][0], acc[i][1], acc[i][2], acc[i][3]);
            *(float4*)(dstp + 64 + tc * 4) = make_float4(acc[i][4], acc[i][5], acc[i][6], acc[i][7]);
        }
    }
}

// ---------------------------------------------------------------- aggregation (unroll-8, norm on the fly):
// H[i] = sum_e dinv[src_e]*dinv[i] * T[src_e] + dinv[i]^2 * T[i] + b ; optional relu
__global__ __launch_bounds__(256) void k_agg(const float* __restrict__ T, float* __restrict__ H,
                                             const int* __restrict__ start,
                                             const int* __restrict__ csr_src,
                                             const float* __restrict__ dinv,
                                             const float* __restrict__ bias,
                                             int relu, int nnodes) {
    int g = (blockIdx.x * blockDim.x + threadIdx.x) >> 5;
    int lane = threadIdx.x & 31;
    if (g >= nnodes) return;
    const size_t loff = (size_t)lane * 4;
    float di = dinv[g];
    float4 v = *(const float4*)&T[(size_t)g * 128 + loff];
    float self = di * di;
    float ax = self * v.x, ay = self * v.y, az = self * v.z, aw = self * v.w;
    int e0 = start[g], e1 = start[g + 1];
    int e = e0;
    for (; e + 8 <= e1; e += 8) {
        int   s[8];
        float w[8];
        float4 u[8];
#pragma unroll
        for (int j = 0; j < 8; ++j) s[j] = csr_src[e + j];
#pragma unroll
        for (int j = 0; j < 8; ++j) u[j] = *(const float4*)&T[(size_t)s[j] * 128 + loff];
#pragma unroll
        for (int j = 0; j < 8; ++j) w[j] = dinv[s[j]] * di;
#pragma unroll
        for (int j = 0; j < 8; ++j) {
            ax += w[j] * u[j].x; ay += w[j] * u[j].y;
            az += w[j] * u[j].z; aw += w[j] * u[j].w;
        }
    }
    if (e + 4 <= e1) {
        int   s[4];
        float w[4];
        float4 u[4];
#pragma unroll
        for (int j = 0; j < 4; ++j) s[j] = csr_src[e + j];
#pragma unroll
        for (int j = 0; j < 4; ++j) u[j] = *(const float4*)&T[(size_t)s[j] * 128 + loff];
#pragma unroll
        for (int j = 0; j < 4; ++j) w[j] = dinv[s[j]] * di;
#pragma unroll
        for (int j = 0; j < 4; ++j) {
            ax += w[j] * u[j].x; ay += w[j] * u[j].y;
            az += w[j] * u[j].z; aw += w[j] * u[j].w;
        }
        e += 4;
    }
    for (; e < e1; ++e) {
        int s = csr_src[e];
        float w = dinv[s] * di;
        float4 u = *(const float4*)&T[(size_t)s * 128 + loff];
        ax += w * u.x; ay += w * u.y; az += w * u.z; aw += w * u.w;
    }
    float4 b = *(const float4*)&bias[loff];
    ax += b.x; ay += b.y; az += b.z; aw += b.w;
    if (relu) {
        ax = fmaxf(ax, 0.f); ay = fmaxf(ay, 0.f);
        az = fmaxf(az, 0.f); aw = fmaxf(aw, 0.f);
    }
    *(float4*)&H[(size_t)g * 128 + loff] = make_float4(ax, ay, az, aw);
}

// ---------------------------------------------------------------- pooling: batch sorted -> register accumulate, flush per boundary
__global__ __launch_bounds__(128) void k_pool(const float* __restrict__ H,
                                              const int* __restrict__ batch,
                                              float* __restrict__ gsum,
                                              float* __restrict__ gcnt, int nnodes) {
    int d = threadIdx.x;                 // 0..127
    int per = (nnodes + gridDim.x - 1) / gridDim.x;
    int n0 = blockIdx.x * per;
    int n1 = min(nnodes, n0 + per);
    if (n0 >= n1) return;
    int cur = batch[n0];
    float acc = 0.f;
    int cnt = 0;
    for (int n = n0; n < n1; ++n) {
        int b = batch[n];
        if (b != cur) {
            atomicAdd(&gsum[cur * HIDDEN + d], acc);
            if (d == 0) atomicAdd(&gcnt[cur], (float)cnt);
            acc = 0.f; cnt = 0; cur = b;
        }
        acc += H[(size_t)n * HIDDEN + d];
        cnt++;
    }
    atomicAdd(&gsum[cur * HIDDEN + d], acc);
    if (d == 0) atomicAdd(&gcnt[cur], (float)cnt);
}

// ---------------------------------------------------------------- final: out[64,2] = (gsum/cnt) @ Wl + bl
__global__ __launch_bounds__(128) void k_final(const float* __restrict__ gsum,
                                               const float* __restrict__ gcnt,
                                               const float* __restrict__ Wl,
                                               const float* __restrict__ bl,
                                               float* __restrict__ out) {
    int tid = threadIdx.x;               // 0..127
    int g = tid >> 1;
    int c = tid & 1;
    float inv = 1.0f / fmaxf(gcnt[g], 1.0f);
    float acc = 0.f;
#pragma unroll 8
    for (int k = 0; k < HIDDEN; ++k)
        acc += gsum[g * HIDDEN + k] * Wl[k * N_CLASSES + c];
    out[g * N_CLASSES + c] = acc * inv + bl[c];
}

// ================================================================ launch
extern "C" void kernel_launch(void* const* d_in, const int* in_sizes, int n_in,
                              void* d_out, int out_size, void* d_ws, size_t ws_size,
                              hipStream_t stream) {
    const float* x    = (const float*)d_in[0];
    const int*   ei   = (const int*)d_in[1];
    const int*   batch= (const int*)d_in[2];
    const float* W1   = (const float*)d_in[3];
    const float* b1   = (const float*)d_in[4];
    const float* W2   = (const float*)d_in[5];
    const float* b2   = (const float*)d_in[6];
    const float* W3   = (const float*)d_in[7];
    const float* b3   = (const float*)d_in[8];
    const float* Wl   = (const float*)d_in[9];
    const float* bl   = (const float*)d_in[10];
    float* out = (float*)d_out;

    const int N = in_sizes[0] / N_FEAT;        // 40000
    const int E = in_sizes[1] / 2;             // 640000
    const int* e_src = ei;
    const int* e_dst = ei + E;
    const int B = (N + SCAN_TILE - 1) / SCAN_TILE;   // 40 scan blocks (<=1024 required)

    // workspace carve-out (256B aligned)
    char* ws = (char*)d_ws;
    auto carve = [&](size_t bytes) -> char* {
        char* p = ws;
        ws += (bytes + 255) & ~(size_t)255;
        return p;
    };
    float* T        = (float*)carve((size_t)N * HIDDEN * 4);
    float* H        = (float*)carve((size_t)N * HIDDEN * 4);
    int*   deg      = (int*)  carve((size_t)N * 4);
    int*   start    = (int*)  carve((size_t)(N + 1) * 4);
    int*   cursor   = (int*)  carve((size_t)N * 4);
    float* dinv     = (float*)carve((size_t)N * 4);
    int*   csr_src  = (int*)  carve((size_t)E * 4);
    float* gsum     = (float*)carve((size_t)N_GRAPHS * HIDDEN * 4);
    float* gcnt     = (float*)carve((size_t)N_GRAPHS * 4);
    int*   bsum     = (int*)  carve((size_t)B * 4);
    int*   boff     = (int*)  carve((size_t)B * 4);
    if ((size_t)(ws - (char*)d_ws) > ws_size) return;

    // --- CSR build ---
    k_zero  <<<(N + 255) / 256, 256, 0, stream>>>(deg, gsum, gcnt, N);
    k_count <<<(E / 4 + 255) / 256, 256, 0, stream>>>(e_dst, deg, E);
    k_scan_a<<<B, 1024, 0, stream>>>(deg, bsum, N);
    k_scan_b<<<1, 1024, 0, stream>>>(bsum, boff, start, B, N);
    k_scan_c<<<B, 1024, 0, stream>>>(deg, boff, start, cursor, dinv, N);
    k_fill  <<<(E / 4 + 255) / 256, 256, 0, stream>>>(e_src, e_dst, cursor, csr_src, E);

    const int aggBlocks  = (N * 32 + 255) / 256;          // 32 lanes/node
    const int gemmBlocks = (N + 63) / 64;                 // 64 rows/block

    // --- layer 1 ---
    k_gemm7<<<(N + 1) / 2, 256, 0, stream>>>(x, W1, T, N);
    k_agg  <<<aggBlocks, 256, 0, stream>>>(T, H, start, csr_src, dinv, b1, 1, N);
    // --- layer 2 ---
    k_gemm128<<<gemmBlocks, 256, 0, stream>>>(H, W2, T, N);
    k_agg    <<<aggBlocks, 256, 0, stream>>>(T, H, start, csr_src, dinv, b2, 1, N);
    // --- layer 3 (no relu) ---
    k_gemm128<<<gemmBlocks, 256, 0, stream>>>(H, W3, T, N);
    k_agg    <<<aggBlocks, 256, 0, stream>>>(T, H, start, csr_src, dinv, b3, 0, N);

    // --- pool + classifier ---
    k_pool <<<256, 128, 0, stream>>>(H, batch, gsum, gcnt, N);
    k_final<<<1, 128, 0, stream>>>(gsum, gcnt, Wl, bl, out);
}

// Round 7
// 292.467 us; speedup vs baseline: 1.6365x; 1.1471x over previous
//
#include <hip/hip_runtime.h>
#include <hip/hip_bf16.h>

#define N_FEAT 7
#define HIDDEN 128
#define N_CLASSES 2
#define N_GRAPHS 64
#define SCAN_TILE 1024

// ---------------------------------------------------------------- zero init
__global__ void k_zero(int* __restrict__ deg, float* __restrict__ gsum,
                       float* __restrict__ gcnt, int n) {
    int i = blockIdx.x * blockDim.x + threadIdx.x;
    if (i < n) deg[i] = 0;
    if (i < N_GRAPHS * HIDDEN) gsum[i] = 0.f;
    if (i < N_GRAPHS) gcnt[i] = 0.f;
}

// ---------------------------------------------------------------- degree count (4 edges/thread)
__global__ void k_count(const int* __restrict__ dst, int* __restrict__ deg, int E) {
    int e4 = (blockIdx.x * blockDim.x + threadIdx.x) << 2;
    if (e4 + 4 <= E) {
        int4 d = *(const int4*)&dst[e4];
        atomicAdd(&deg[d.x], 1);
        atomicAdd(&deg[d.y], 1);
        atomicAdd(&deg[d.z], 1);
        atomicAdd(&deg[d.w], 1);
    } else {
        for (int e = e4; e < E; ++e) atomicAdd(&deg[dst[e]], 1);
    }
}

// ---------------------------------------------------------------- scan phase A: per-block sums
__global__ __launch_bounds__(1024) void k_scan_a(const int* __restrict__ deg,
                                                 int* __restrict__ bsum, int n) {
    __shared__ int s[SCAN_TILE];
    int tid = threadIdx.x;
    int i = blockIdx.x * SCAN_TILE + tid;
    s[tid] = (i < n) ? deg[i] : 0;
    __syncthreads();
#pragma unroll
    for (int off = 512; off > 0; off >>= 1) {
        if (tid < off) s[tid] += s[tid + off];
        __syncthreads();
    }
    if (tid == 0) bsum[blockIdx.x] = s[0];
}

// ---------------------------------------------------------------- scan phase B: scan of block sums (1 block; B <= 1024)
__global__ __launch_bounds__(1024) void k_scan_b(const int* __restrict__ bsum,
                                                 int* __restrict__ boff,
                                                 int* __restrict__ start, int B, int n) {
    __shared__ int s[SCAN_TILE];
    int tid = threadIdx.x;
    int v = (tid < B) ? bsum[tid] : 0;
    s[tid] = v;
    __syncthreads();
    for (int off = 1; off < SCAN_TILE; off <<= 1) {
        int t = (tid >= off) ? s[tid - off] : 0;
        __syncthreads();
        s[tid] += t;
        __syncthreads();
    }
    if (tid < B) boff[tid] = s[tid] - v;       // exclusive
    if (tid == B - 1) start[n] = s[tid];       // total = E
}

// ---------------------------------------------------------------- scan phase C: block-local scan + offset; write start/cursor/dinv
__global__ __launch_bounds__(1024) void k_scan_c(const int* __restrict__ deg,
                                                 const int* __restrict__ boff,
                                                 int* __restrict__ start,
                                                 int* __restrict__ cursor,
                                                 float* __restrict__ dinv, int n) {
    __shared__ int s[SCAN_TILE];
    int tid = threadIdx.x;
    int i = blockIdx.x * SCAN_TILE + tid;
    int v = (i < n) ? deg[i] : 0;
    s[tid] = v;
    __syncthreads();
    for (int off = 1; off < SCAN_TILE; off <<= 1) {
        int t = (tid >= off) ? s[tid - off] : 0;
        __syncthreads();
        s[tid] += t;
        __syncthreads();
    }
    if (i < n) {
        int ex = boff[blockIdx.x] + s[tid] - v;   // exclusive prefix
        start[i] = ex;
        cursor[i] = ex;
        dinv[i] = rsqrtf((float)(v + 1));
    }
}

// ---------------------------------------------------------------- CSR fill: src index only
__global__ void k_fill(const int* __restrict__ src, const int* __restrict__ dst,
                       int* __restrict__ cursor, int* __restrict__ csr_src, int E) {
    int e4 = (blockIdx.x * blockDim.x + threadIdx.x) << 2;
    if (e4 + 4 <= E) {
        int4 s = *(const int4*)&src[e4];
        int4 d = *(const int4*)&dst[e4];
        csr_src[atomicAdd(&cursor[d.x], 1)] = s.x;
        csr_src[atomicAdd(&cursor[d.y], 1)] = s.y;
        csr_src[atomicAdd(&cursor[d.z], 1)] = s.z;
        csr_src[atomicAdd(&cursor[d.w], 1)] = s.w;
    } else {
        for (int e = e4; e < E; ++e)
            csr_src[atomicAdd(&cursor[dst[e]], 1)] = src[e];
    }
}

// ---------------------------------------------------------------- prep: xp[i][j] = dinv[i]*x[i][j] (j<7), 0 pad to 8
__global__ void k_prep(const float* __restrict__ x, const float* __restrict__ dinv,
                       float* __restrict__ xp, int n) {
    int t = blockIdx.x * blockDim.x + threadIdx.x;
    int i = t >> 3, j = t & 7;
    if (i >= n) return;
    xp[t] = (j < N_FEAT) ? dinv[i] * x[i * N_FEAT + j] : 0.f;
}

// ---------------------------------------------------------------- layer-1 aggregation on 7-dim features (xp L2-resident):
// ax[i] = dinv[i] * (sum_src xp[src] + xp[i])   [N,8]
__global__ __launch_bounds__(256) void k_agg7(const float* __restrict__ xp,
                                              float* __restrict__ ax,
                                              const int* __restrict__ start,
                                              const int* __restrict__ csr_src,
                                              const float* __restrict__ dinv, int nnodes) {
    int t = blockIdx.x * blockDim.x + threadIdx.x;
    int g = t >> 3, j = t & 7;
    if (g >= nnodes) return;
    float acc = xp[(size_t)g * 8 + j];          // self
    int e0 = start[g], e1 = start[g + 1];
    int e = e0;
    for (; e + 4 <= e1; e += 4) {
        int s0 = csr_src[e + 0], s1 = csr_src[e + 1];
        int s2 = csr_src[e + 2], s3 = csr_src[e + 3];
        float u0 = xp[(size_t)s0 * 8 + j];
        float u1 = xp[(size_t)s1 * 8 + j];
        float u2 = xp[(size_t)s2 * 8 + j];
        float u3 = xp[(size_t)s3 * 8 + j];
        acc += u0 + u1 + u2 + u3;
    }
    for (; e < e1; ++e) acc += xp[(size_t)csr_src[e] * 8 + j];
    ax[(size_t)g * 8 + j] = dinv[g] * acc;
}

// ---------------------------------------------------------------- layer-1 transform: h1 = relu(ax[N,8(7)] @ W1[7,128] + b1)
__global__ __launch_bounds__(256) void k_gemm7(const float* __restrict__ AX,
                                               const float* __restrict__ W1,
                                               const float* __restrict__ b1,
                                               float* __restrict__ h1, int n) {
    __shared__ float w[N_FEAT * HIDDEN];
    __shared__ float bs[HIDDEN];
    int tid = threadIdx.x;
    for (int i = tid; i < N_FEAT * HIDDEN; i += 256) w[i] = W1[i];
    if (tid < HIDDEN) bs[tid] = b1[tid];
    __syncthreads();
    int row = blockIdx.x * 2 + (tid >> 7);
    int col = tid & 127;
    if (row >= n) return;
    float acc = bs[col];
#pragma unroll
    for (int k = 0; k < N_FEAT; ++k)
        acc += AX[(size_t)row * 8 + k] * w[k * HIDDEN + col];
    h1[(size_t)row * HIDDEN + col] = fmaxf(acc, 0.f);
}

// ---------------------------------------------------------------- dense fp32 GEMM with dinv pre-scale epilogue:
// Ts[i] = dinv[i] * (A[i] @ W)   (bias/relu applied later in agg)
__global__ __launch_bounds__(256) void k_gemm128(const float* __restrict__ A,
                                                 const float* __restrict__ W,
                                                 const float* __restrict__ dinv,
                                                 float* __restrict__ Ts, int nrows) {
    __shared__ float as[16][68];    // [k][row], padded 64->68
    __shared__ float ws[16][132];   // [k][col], padded 128->132
    int row0 = blockIdx.x * 64;
    int tid = threadIdx.x;
    int tr = tid >> 4;      // rows tr*4..+3
    int tc = tid & 15;      // cols tc*4..+3 and 64+tc*4..+3
    float acc[4][8] = {};
    for (int k0 = 0; k0 < 128; k0 += 16) {
        {
            int r = tid >> 2;
            int ko = (tid & 3) << 2;
            float4 av = make_float4(0.f, 0.f, 0.f, 0.f);
            if (row0 + r < nrows)
                av = *(const float4*)&A[(size_t)(row0 + r) * 128 + k0 + ko];
            as[ko + 0][r] = av.x; as[ko + 1][r] = av.y;
            as[ko + 2][r] = av.z; as[ko + 3][r] = av.w;
        }
        {
            int wk = tid >> 4;
            int wc = (tid & 15) << 2;
            const float* wp = &W[(size_t)(k0 + wk) * 128 + wc];
            *(float4*)&ws[wk][wc]      = *(const float4*)(wp);
            *(float4*)&ws[wk][wc + 64] = *(const float4*)(wp + 64);
        }
        __syncthreads();
#pragma unroll
        for (int kk = 0; kk < 16; ++kk) {
            float a[4], b[8];
            *(float4*)&a[0] = *(const float4*)&as[kk][tr * 4];
            *(float4*)&b[0] = *(const float4*)&ws[kk][tc * 4];
            *(float4*)&b[4] = *(const float4*)&ws[kk][64 + tc * 4];
#pragma unroll
            for (int i = 0; i < 4; ++i)
#pragma unroll
                for (int j = 0; j < 8; ++j)
                    acc[i][j] += a[i] * b[j];
        }
        __syncthreads();
    }
#pragma unroll
    for (int i = 0; i < 4; ++i) {
        int rr = row0 + tr * 4 + i;
        if (rr < nrows) {
            float sc = dinv[rr];
            float* dstp = &Ts[(size_t)rr * 128];
            *(float4*)(dstp + tc * 4)      = make_float4(sc * acc[i][0], sc * acc[i][1], sc * acc[i][2], sc * acc[i][3]);
            *(float4*)(dstp + 64 + tc * 4) = make_float4(sc * acc[i][4], sc * acc[i][5], sc * acc[i][6], sc * acc[i][7]);
        }
    }
}

// ---------------------------------------------------------------- aggregation on pre-scaled Ts:
// H[i] = dinv[i] * (sum_src Ts[src] + Ts[i]) + b ; optional relu
__global__ __launch_bounds__(256) void k_agg(const float* __restrict__ Ts, float* __restrict__ H,
                                             const int* __restrict__ start,
                                             const int* __restrict__ csr_src,
                                             const float* __restrict__ dinv,
                                             const float* __restrict__ bias,
                                             int relu, int nnodes) {
    int g = (blockIdx.x * blockDim.x + threadIdx.x) >> 5;
    int lane = threadIdx.x & 31;
    if (g >= nnodes) return;
    const size_t loff = (size_t)lane * 4;
    float4 v = *(const float4*)&Ts[(size_t)g * 128 + loff];   // self
    float ax = v.x, ay = v.y, az = v.z, aw = v.w;
    int e0 = start[g], e1 = start[g + 1];
    int e = e0;
    for (; e + 8 <= e1; e += 8) {
        int s[8];
        float4 u[8];
#pragma unroll
        for (int j = 0; j < 8; ++j) s[j] = csr_src[e + j];
#pragma unroll
        for (int j = 0; j < 8; ++j) u[j] = *(const float4*)&Ts[(size_t)s[j] * 128 + loff];
#pragma unroll
        for (int j = 0; j < 8; ++j) {
            ax += u[j].x; ay += u[j].y; az += u[j].z; aw += u[j].w;
        }
    }
    if (e + 4 <= e1) {
        int s[4];
        float4 u[4];
#pragma unroll
        for (int j = 0; j < 4; ++j) s[j] = csr_src[e + j];
#pragma unroll
        for (int j = 0; j < 4; ++j) u[j] = *(const float4*)&Ts[(size_t)s[j] * 128 + loff];
#pragma unroll
        for (int j = 0; j < 4; ++j) {
            ax += u[j].x; ay += u[j].y; az += u[j].z; aw += u[j].w;
        }
        e += 4;
    }
    for (; e < e1; ++e) {
        float4 u = *(const float4*)&Ts[(size_t)csr_src[e] * 128 + loff];
        ax += u.x; ay += u.y; az += u.z; aw += u.w;
    }
    float di = dinv[g];
    float4 b = *(const float4*)&bias[loff];
    ax = di * ax + b.x; ay = di * ay + b.y;
    az = di * az + b.z; aw = di * aw + b.w;
    if (relu) {
        ax = fmaxf(ax, 0.f); ay = fmaxf(ay, 0.f);
        az = fmaxf(az, 0.f); aw = fmaxf(aw, 0.f);
    }
    *(float4*)&H[(size_t)g * 128 + loff] = make_float4(ax, ay, az, aw);
}

// ---------------------------------------------------------------- pooling: batch sorted -> register accumulate, flush per boundary
__global__ __launch_bounds__(128) void k_pool(const float* __restrict__ H,
                                              const int* __restrict__ batch,
                                              float* __restrict__ gsum,
                                              float* __restrict__ gcnt, int nnodes) {
    int d = threadIdx.x;                 // 0..127
    int per = (nnodes + gridDim.x - 1) / gridDim.x;
    int n0 = blockIdx.x * per;
    int n1 = min(nnodes, n0 + per);
    if (n0 >= n1) return;
    int cur = batch[n0];
    float acc = 0.f;
    int cnt = 0;
    for (int n = n0; n < n1; ++n) {
        int b = batch[n];
        if (b != cur) {
            atomicAdd(&gsum[cur * HIDDEN + d], acc);
            if (d == 0) atomicAdd(&gcnt[cur], (float)cnt);
            acc = 0.f; cnt = 0; cur = b;
        }
        acc += H[(size_t)n * HIDDEN + d];
        cnt++;
    }
    atomicAdd(&gsum[cur * HIDDEN + d], acc);
    if (d == 0) atomicAdd(&gcnt[cur], (float)cnt);
}

// ---------------------------------------------------------------- final: out[64,2] = (gsum/cnt) @ Wl + bl
__global__ __launch_bounds__(128) void k_final(const float* __restrict__ gsum,
                                               const float* __restrict__ gcnt,
                                               const float* __restrict__ Wl,
                                               const float* __restrict__ bl,
                                               float* __restrict__ out) {
    int tid = threadIdx.x;               // 0..127
    int g = tid >> 1;
    int c = tid & 1;
    float inv = 1.0f / fmaxf(gcnt[g], 1.0f);
    float acc = 0.f;
#pragma unroll 8
    for (int k = 0; k < HIDDEN; ++k)
        acc += gsum[g * HIDDEN + k] * Wl[k * N_CLASSES + c];
    out[g * N_CLASSES + c] = acc * inv + bl[c];
}

// ================================================================ launch
extern "C" void kernel_launch(void* const* d_in, const int* in_sizes, int n_in,
                              void* d_out, int out_size, void* d_ws, size_t ws_size,
                              hipStream_t stream) {
    const float* x    = (const float*)d_in[0];
    const int*   ei   = (const int*)d_in[1];
    const int*   batch= (const int*)d_in[2];
    const float* W1   = (const float*)d_in[3];
    const float* b1   = (const float*)d_in[4];
    const float* W2   = (const float*)d_in[5];
    const float* b2   = (const float*)d_in[6];
    const float* W3   = (const float*)d_in[7];
    const float* b3   = (const float*)d_in[8];
    const float* Wl   = (const float*)d_in[9];
    const float* bl   = (const float*)d_in[10];
    float* out = (float*)d_out;

    const int N = in_sizes[0] / N_FEAT;        // 40000
    const int E = in_sizes[1] / 2;             // 640000
    const int* e_src = ei;
    const int* e_dst = ei + E;
    const int B = (N + SCAN_TILE - 1) / SCAN_TILE;   // 40 scan blocks

    // workspace carve-out (256B aligned)
    char* ws = (char*)d_ws;
    auto carve = [&](size_t bytes) -> char* {
        char* p = ws;
        ws += (bytes + 255) & ~(size_t)255;
        return p;
    };
    float* T        = (float*)carve((size_t)N * HIDDEN * 4);   // Ts (pre-scaled transform)
    float* H        = (float*)carve((size_t)N * HIDDEN * 4);
    float* xp       = (float*)carve((size_t)N * 8 * 4);
    float* ax       = (float*)carve((size_t)N * 8 * 4);
    int*   deg      = (int*)  carve((size_t)N * 4);
    int*   start    = (int*)  carve((size_t)(N + 1) * 4);
    int*   cursor   = (int*)  carve((size_t)N * 4);
    float* dinv     = (float*)carve((size_t)N * 4);
    int*   csr_src  = (int*)  carve((size_t)E * 4);
    float* gsum     = (float*)carve((size_t)N_GRAPHS * HIDDEN * 4);
    float* gcnt     = (float*)carve((size_t)N_GRAPHS * 4);
    int*   bsum     = (int*)  carve((size_t)B * 4);
    int*   boff     = (int*)  carve((size_t)B * 4);
    if ((size_t)(ws - (char*)d_ws) > ws_size) return;

    // --- CSR build ---
    k_zero  <<<(N + 255) / 256, 256, 0, stream>>>(deg, gsum, gcnt, N);
    k_count <<<(E / 4 + 255) / 256, 256, 0, stream>>>(e_dst, deg, E);
    k_scan_a<<<B, 1024, 0, stream>>>(deg, bsum, N);
    k_scan_b<<<1, 1024, 0, stream>>>(bsum, boff, start, B, N);
    k_scan_c<<<B, 1024, 0, stream>>>(deg, boff, start, cursor, dinv, N);
    k_fill  <<<(E / 4 + 255) / 256, 256, 0, stream>>>(e_src, e_dst, cursor, csr_src, E);

    const int aggBlocks  = (N * 32 + 255) / 256;          // 32 lanes/node
    const int gemmBlocks = (N + 63) / 64;                 // 64 rows/block

    // --- layer 1: aggregate 7-dim, then transform ---
    k_prep <<<(N * 8 + 255) / 256, 256, 0, stream>>>(x, dinv, xp, N);
    k_agg7 <<<(N * 8 + 255) / 256, 256, 0, stream>>>(xp, ax, start, csr_src, dinv, N);
    k_gemm7<<<(N + 1) / 2, 256, 0, stream>>>(ax, W1, b1, H, N);   // H = h1
    // --- layer 2 ---
    k_gemm128<<<gemmBlocks, 256, 0, stream>>>(H, W2, dinv, T, N); // T = dinv*(h1@W2)
    k_agg    <<<aggBlocks, 256, 0, stream>>>(T, H, start, csr_src, dinv, b2, 1, N);
    // --- layer 3 (no relu) ---
    k_gemm128<<<gemmBlocks, 256, 0, stream>>>(H, W3, dinv, T, N);
    k_agg    <<<aggBlocks, 256, 0, stream>>>(T, H, start, csr_src, dinv, b3, 0, N);

    // --- pool + classifier ---
    k_pool <<<256, 128, 0, stream>>>(H, batch, gsum, gcnt, N);
    k_final<<<1, 128, 0, stream>>>(gsum, gcnt, Wl, bl, out);
}

// Round 8
// 259.820 us; speedup vs baseline: 1.8421x; 1.1257x over previous
//
#include <hip/hip_runtime.h>
#include <hip/hip_bf16.h>

#define N_FEAT 7
#define HIDDEN 128
#define N_CLASSES 2
#define N_GRAPHS 64
#define SCAN_TILE 1024

// ---------------------------------------------------------------- zero init
__global__ void k_zero(int* __restrict__ deg, float* __restrict__ gsum, int n) {
    int i = blockIdx.x * blockDim.x + threadIdx.x;
    if (i < n) deg[i] = 0;
    if (i < N_GRAPHS * HIDDEN) gsum[i] = 0.f;
}

// ---------------------------------------------------------------- degree count (4 edges/thread)
__global__ void k_count(const int* __restrict__ dst, int* __restrict__ deg, int E) {
    int e4 = (blockIdx.x * blockDim.x + threadIdx.x) << 2;
    if (e4 + 4 <= E) {
        int4 d = *(const int4*)&dst[e4];
        atomicAdd(&deg[d.x], 1);
        atomicAdd(&deg[d.y], 1);
        atomicAdd(&deg[d.z], 1);
        atomicAdd(&deg[d.w], 1);
    } else {
        for (int e = e4; e < E; ++e) atomicAdd(&deg[dst[e]], 1);
    }
}

// ---------------------------------------------------------------- scan phase A: per-block sums
__global__ __launch_bounds__(1024) void k_scan_a(const int* __restrict__ deg,
                                                 int* __restrict__ bsum, int n) {
    __shared__ int s[SCAN_TILE];
    int tid = threadIdx.x;
    int i = blockIdx.x * SCAN_TILE + tid;
    s[tid] = (i < n) ? deg[i] : 0;
    __syncthreads();
#pragma unroll
    for (int off = 512; off > 0; off >>= 1) {
        if (tid < off) s[tid] += s[tid + off];
        __syncthreads();
    }
    if (tid == 0) bsum[blockIdx.x] = s[0];
}

// ---------------------------------------------------------------- scan phase B: scan of block sums (1 block; B <= 1024)
__global__ __launch_bounds__(1024) void k_scan_b(const int* __restrict__ bsum,
                                                 int* __restrict__ boff,
                                                 int* __restrict__ start, int B, int n) {
    __shared__ int s[SCAN_TILE];
    int tid = threadIdx.x;
    int v = (tid < B) ? bsum[tid] : 0;
    s[tid] = v;
    __syncthreads();
    for (int off = 1; off < SCAN_TILE; off <<= 1) {
        int t = (tid >= off) ? s[tid - off] : 0;
        __syncthreads();
        s[tid] += t;
        __syncthreads();
    }
    if (tid < B) boff[tid] = s[tid] - v;       // exclusive
    if (tid == B - 1) start[n] = s[tid];       // total = E
}

// ---------------------------------------------------------------- scan phase C: block-local scan + offset; write start/cursor/dinv
__global__ __launch_bounds__(1024) void k_scan_c(const int* __restrict__ deg,
                                                 const int* __restrict__ boff,
                                                 int* __restrict__ start,
                                                 int* __restrict__ cursor,
                                                 float* __restrict__ dinv, int n) {
    __shared__ int s[SCAN_TILE];
    int tid = threadIdx.x;
    int i = blockIdx.x * SCAN_TILE + tid;
    int v = (i < n) ? deg[i] : 0;
    s[tid] = v;
    __syncthreads();
    for (int off = 1; off < SCAN_TILE; off <<= 1) {
        int t = (tid >= off) ? s[tid - off] : 0;
        __syncthreads();
        s[tid] += t;
        __syncthreads();
    }
    if (i < n) {
        int ex = boff[blockIdx.x] + s[tid] - v;   // exclusive prefix
        start[i] = ex;
        cursor[i] = ex;
        dinv[i] = rsqrtf((float)(v + 1));
    }
}

// ---------------------------------------------------------------- CSR fill: src index only
__global__ void k_fill(const int* __restrict__ src, const int* __restrict__ dst,
                       int* __restrict__ cursor, int* __restrict__ csr_src, int E) {
    int e4 = (blockIdx.x * blockDim.x + threadIdx.x) << 2;
    if (e4 + 4 <= E) {
        int4 s = *(const int4*)&src[e4];
        int4 d = *(const int4*)&dst[e4];
        csr_src[atomicAdd(&cursor[d.x], 1)] = s.x;
        csr_src[atomicAdd(&cursor[d.y], 1)] = s.y;
        csr_src[atomicAdd(&cursor[d.z], 1)] = s.z;
        csr_src[atomicAdd(&cursor[d.w], 1)] = s.w;
    } else {
        for (int e = e4; e < E; ++e)
            csr_src[atomicAdd(&cursor[dst[e]], 1)] = src[e];
    }
}

// ---------------------------------------------------------------- graph boundaries: goff[g] = lower_bound(batch, g); goff[64] = n
__global__ void k_bounds(const int* __restrict__ batch, int* __restrict__ goff, int n) {
    int g = threadIdx.x;
    if (g > N_GRAPHS) return;
    int lo = 0, hi = n;
    while (lo < hi) {
        int m = (lo + hi) >> 1;
        if (batch[m] < g) lo = m + 1; else hi = m;
    }
    goff[g] = lo;
}

// ---------------------------------------------------------------- prep: xp[i][j] = dinv[i]*x[i][j] (j<7), 0 pad to 8
__global__ void k_prep(const float* __restrict__ x, const float* __restrict__ dinv,
                       float* __restrict__ xp, int n) {
    int t = blockIdx.x * blockDim.x + threadIdx.x;
    int i = t >> 3, j = t & 7;
    if (i >= n) return;
    xp[t] = (j < N_FEAT) ? dinv[i] * x[i * N_FEAT + j] : 0.f;
}

// ---------------------------------------------------------------- layer-1 aggregation on 7-dim features (xp L2-resident):
// ax[i] = dinv[i] * (sum_src xp[src] + xp[i])   [N,8]
__global__ __launch_bounds__(256) void k_agg7(const float* __restrict__ xp,
                                              float* __restrict__ ax,
                                              const int* __restrict__ start,
                                              const int* __restrict__ csr_src,
                                              const float* __restrict__ dinv, int nnodes) {
    int t = blockIdx.x * blockDim.x + threadIdx.x;
    int g = t >> 3, j = t & 7;
    if (g >= nnodes) return;
    float acc = xp[(size_t)g * 8 + j];          // self
    int e0 = start[g], e1 = start[g + 1];
    int e = e0;
    for (; e + 4 <= e1; e += 4) {
        int s0 = csr_src[e + 0], s1 = csr_src[e + 1];
        int s2 = csr_src[e + 2], s3 = csr_src[e + 3];
        float u0 = xp[(size_t)s0 * 8 + j];
        float u1 = xp[(size_t)s1 * 8 + j];
        float u2 = xp[(size_t)s2 * 8 + j];
        float u3 = xp[(size_t)s3 * 8 + j];
        acc += u0 + u1 + u2 + u3;
    }
    for (; e < e1; ++e) acc += xp[(size_t)csr_src[e] * 8 + j];
    ax[(size_t)g * 8 + j] = dinv[g] * acc;
}

// ---------------------------------------------------------------- layer-1 transform: h1 = relu(ax[N,8(7)] @ W1[7,128] + b1)
__global__ __launch_bounds__(256) void k_gemm7(const float* __restrict__ AX,
                                               const float* __restrict__ W1,
                                               const float* __restrict__ b1,
                                               float* __restrict__ h1, int n) {
    __shared__ float w[N_FEAT * HIDDEN];
    __shared__ float bs[HIDDEN];
    int tid = threadIdx.x;
    for (int i = tid; i < N_FEAT * HIDDEN; i += 256) w[i] = W1[i];
    if (tid < HIDDEN) bs[tid] = b1[tid];
    __syncthreads();
    int row = blockIdx.x * 2 + (tid >> 7);
    int col = tid & 127;
    if (row >= n) return;
    float acc = bs[col];
#pragma unroll
    for (int k = 0; k < N_FEAT; ++k)
        acc += AX[(size_t)row * 8 + k] * w[k * HIDDEN + col];
    h1[(size_t)row * HIDDEN + col] = fmaxf(acc, 0.f);
}

// ---------------------------------------------------------------- dense fp32 GEMM with dinv pre-scale epilogue:
// Ts[i] = dinv[i] * (A[i] @ W)
__global__ __launch_bounds__(256) void k_gemm128(const float* __restrict__ A,
                                                 const float* __restrict__ W,
                                                 const float* __restrict__ dinv,
                                                 float* __restrict__ Ts, int nrows) {
    __shared__ float as[16][68];    // [k][row], padded 64->68
    __shared__ float ws[16][132];   // [k][col], padded 128->132
    int row0 = blockIdx.x * 64;
    int tid = threadIdx.x;
    int tr = tid >> 4;      // rows tr*4..+3
    int tc = tid & 15;      // cols tc*4..+3 and 64+tc*4..+3
    float acc[4][8] = {};
    for (int k0 = 0; k0 < 128; k0 += 16) {
        {
            int r = tid >> 2;
            int ko = (tid & 3) << 2;
            float4 av = make_float4(0.f, 0.f, 0.f, 0.f);
            if (row0 + r < nrows)
                av = *(const float4*)&A[(size_t)(row0 + r) * 128 + k0 + ko];
            as[ko + 0][r] = av.x; as[ko + 1][r] = av.y;
            as[ko + 2][r] = av.z; as[ko + 3][r] = av.w;
        }
        {
            int wk = tid >> 4;
            int wc = (tid & 15) << 2;
            const float* wp = &W[(size_t)(k0 + wk) * 128 + wc];
            *(float4*)&ws[wk][wc]      = *(const float4*)(wp);
            *(float4*)&ws[wk][wc + 64] = *(const float4*)(wp + 64);
        }
        __syncthreads();
#pragma unroll
        for (int kk = 0; kk < 16; ++kk) {
            float a[4], b[8];
            *(float4*)&a[0] = *(const float4*)&as[kk][tr * 4];
            *(float4*)&b[0] = *(const float4*)&ws[kk][tc * 4];
            *(float4*)&b[4] = *(const float4*)&ws[kk][64 + tc * 4];
#pragma unroll
            for (int i = 0; i < 4; ++i)
#pragma unroll
                for (int j = 0; j < 8; ++j)
                    acc[i][j] += a[i] * b[j];
        }
        __syncthreads();
    }
#pragma unroll
    for (int i = 0; i < 4; ++i) {
        int rr = row0 + tr * 4 + i;
        if (rr < nrows) {
            float sc = dinv[rr];
            float* dstp = &Ts[(size_t)rr * 128];
            *(float4*)(dstp + tc * 4)      = make_float4(sc * acc[i][0], sc * acc[i][1], sc * acc[i][2], sc * acc[i][3]);
            *(float4*)(dstp + 64 + tc * 4) = make_float4(sc * acc[i][4], sc * acc[i][5], sc * acc[i][6], sc * acc[i][7]);
        }
    }
}

// ---------------------------------------------------------------- aggregation on pre-scaled Ts (unroll 16/8/4):
// H[i] = dinv[i] * (sum_src Ts[src] + Ts[i]) + b ; optional relu
__global__ __launch_bounds__(256) void k_agg(const float* __restrict__ Ts, float* __restrict__ H,
                                             const int* __restrict__ start,
                                             const int* __restrict__ csr_src,
                                             const float* __restrict__ dinv,
                                             const float* __restrict__ bias,
                                             int relu, int nnodes) {
    int g = (blockIdx.x * blockDim.x + threadIdx.x) >> 5;
    int lane = threadIdx.x & 31;
    if (g >= nnodes) return;
    const size_t loff = (size_t)lane * 4;
    float4 v = *(const float4*)&Ts[(size_t)g * 128 + loff];   // self
    float ax = v.x, ay = v.y, az = v.z, aw = v.w;
    int e0 = start[g], e1 = start[g + 1];
    int e = e0;
    for (; e + 16 <= e1; e += 16) {
        int s[16];
        float4 u[16];
#pragma unroll
        for (int j = 0; j < 16; ++j) s[j] = csr_src[e + j];
#pragma unroll
        for (int j = 0; j < 16; ++j) u[j] = *(const float4*)&Ts[(size_t)s[j] * 128 + loff];
#pragma unroll
        for (int j = 0; j < 16; ++j) {
            ax += u[j].x; ay += u[j].y; az += u[j].z; aw += u[j].w;
        }
    }
    if (e + 8 <= e1) {
        int s[8];
        float4 u[8];
#pragma unroll
        for (int j = 0; j < 8; ++j) s[j] = csr_src[e + j];
#pragma unroll
        for (int j = 0; j < 8; ++j) u[j] = *(const float4*)&Ts[(size_t)s[j] * 128 + loff];
#pragma unroll
        for (int j = 0; j < 8; ++j) {
            ax += u[j].x; ay += u[j].y; az += u[j].z; aw += u[j].w;
        }
        e += 8;
    }
    if (e + 4 <= e1) {
        int s[4];
        float4 u[4];
#pragma unroll
        for (int j = 0; j < 4; ++j) s[j] = csr_src[e + j];
#pragma unroll
        for (int j = 0; j < 4; ++j) u[j] = *(const float4*)&Ts[(size_t)s[j] * 128 + loff];
#pragma unroll
        for (int j = 0; j < 4; ++j) {
            ax += u[j].x; ay += u[j].y; az += u[j].z; aw += u[j].w;
        }
        e += 4;
    }
    for (; e < e1; ++e) {
        float4 u = *(const float4*)&Ts[(size_t)csr_src[e] * 128 + loff];
        ax += u.x; ay += u.y; az += u.z; aw += u.w;
    }
    float di = dinv[g];
    float4 b = *(const float4*)&bias[loff];
    ax = di * ax + b.x; ay = di * ay + b.y;
    az = di * az + b.z; aw = di * aw + b.w;
    if (relu) {
        ax = fmaxf(ax, 0.f); ay = fmaxf(ay, 0.f);
        az = fmaxf(az, 0.f); aw = fmaxf(aw, 0.f);
    }
    *(float4*)&H[(size_t)g * 128 + loff] = make_float4(ax, ay, az, aw);
}

// ---------------------------------------------------------------- pooling v2: 8 blocks per graph, 8 groups of 32 lanes each,
// float4/lane register accumulate -> LDS block reduce -> 1 atomic set per block
__global__ __launch_bounds__(256) void k_pool2(const float* __restrict__ H,
                                               const int* __restrict__ goff,
                                               float* __restrict__ gsum) {
    int g   = blockIdx.x >> 3;          // graph
    int sub = blockIdx.x & 7;           // 0..7
    int grp = threadIdx.x >> 5;         // 0..7
    int lane = threadIdx.x & 31;
    int n0 = goff[g], n1 = goff[g + 1];
    float4 acc = make_float4(0.f, 0.f, 0.f, 0.f);
    for (int n = n0 + sub * 8 + grp; n < n1; n += 64) {
        float4 v = *(const float4*)&H[(size_t)n * 128 + lane * 4];
        acc.x += v.x; acc.y += v.y; acc.z += v.z; acc.w += v.w;
    }
    __shared__ float red[8][128];
    *(float4*)&red[grp][lane * 4] = acc;
    __syncthreads();
    if (grp == 0) {
        float4 t = *(const float4*)&red[0][lane * 4];
#pragma unroll
        for (int k = 1; k < 8; ++k) {
            float4 r = *(const float4*)&red[k][lane * 4];
            t.x += r.x; t.y += r.y; t.z += r.z; t.w += r.w;
        }
        atomicAdd(&gsum[g * HIDDEN + lane * 4 + 0], t.x);
        atomicAdd(&gsum[g * HIDDEN + lane * 4 + 1], t.y);
        atomicAdd(&gsum[g * HIDDEN + lane * 4 + 2], t.z);
        atomicAdd(&gsum[g * HIDDEN + lane * 4 + 3], t.w);
    }
}

// ---------------------------------------------------------------- final: out[64,2] = (gsum/cnt) @ Wl + bl  (cnt from goff)
__global__ __launch_bounds__(128) void k_final(const float* __restrict__ gsum,
                                               const int* __restrict__ goff,
                                               const float* __restrict__ Wl,
                                               const float* __restrict__ bl,
                                               float* __restrict__ out) {
    int tid = threadIdx.x;               // 0..127
    int g = tid >> 1;
    int c = tid & 1;
    int cnt = goff[g + 1] - goff[g];
    float inv = 1.0f / (float)max(cnt, 1);
    float acc = 0.f;
#pragma unroll 8
    for (int k = 0; k < HIDDEN; ++k)
        acc += gsum[g * HIDDEN + k] * Wl[k * N_CLASSES + c];
    out[g * N_CLASSES + c] = acc * inv + bl[c];
}

// ================================================================ launch
extern "C" void kernel_launch(void* const* d_in, const int* in_sizes, int n_in,
                              void* d_out, int out_size, void* d_ws, size_t ws_size,
                              hipStream_t stream) {
    const float* x    = (const float*)d_in[0];
    const int*   ei   = (const int*)d_in[1];
    const int*   batch= (const int*)d_in[2];
    const float* W1   = (const float*)d_in[3];
    const float* b1   = (const float*)d_in[4];
    const float* W2   = (const float*)d_in[5];
    const float* b2   = (const float*)d_in[6];
    const float* W3   = (const float*)d_in[7];
    const float* b3   = (const float*)d_in[8];
    const float* Wl   = (const float*)d_in[9];
    const float* bl   = (const float*)d_in[10];
    float* out = (float*)d_out;

    const int N = in_sizes[0] / N_FEAT;        // 40000
    const int E = in_sizes[1] / 2;             // 640000
    const int* e_src = ei;
    const int* e_dst = ei + E;
    const int B = (N + SCAN_TILE - 1) / SCAN_TILE;   // 40 scan blocks

    // workspace carve-out (256B aligned)
    char* ws = (char*)d_ws;
    auto carve = [&](size_t bytes) -> char* {
        char* p = ws;
        ws += (bytes + 255) & ~(size_t)255;
        return p;
    };
    float* T        = (float*)carve((size_t)N * HIDDEN * 4);   // Ts (pre-scaled transform)
    float* H        = (float*)carve((size_t)N * HIDDEN * 4);
    float* xp       = (float*)carve((size_t)N * 8 * 4);
    float* ax       = (float*)carve((size_t)N * 8 * 4);
    int*   deg      = (int*)  carve((size_t)N * 4);
    int*   start    = (int*)  carve((size_t)(N + 1) * 4);
    int*   cursor   = (int*)  carve((size_t)N * 4);
    float* dinv     = (float*)carve((size_t)N * 4);
    int*   csr_src  = (int*)  carve((size_t)E * 4);
    float* gsum     = (float*)carve((size_t)N_GRAPHS * HIDDEN * 4);
    int*   goff     = (int*)  carve((size_t)(N_GRAPHS + 1) * 4);
    int*   bsum     = (int*)  carve((size_t)B * 4);
    int*   boff     = (int*)  carve((size_t)B * 4);
    if ((size_t)(ws - (char*)d_ws) > ws_size) return;

    // --- CSR build + graph bounds ---
    k_zero  <<<(N + 255) / 256, 256, 0, stream>>>(deg, gsum, N);
    k_count <<<(E / 4 + 255) / 256, 256, 0, stream>>>(e_dst, deg, E);
    k_scan_a<<<B, 1024, 0, stream>>>(deg, bsum, N);
    k_scan_b<<<1, 1024, 0, stream>>>(bsum, boff, start, B, N);
    k_scan_c<<<B, 1024, 0, stream>>>(deg, boff, start, cursor, dinv, N);
    k_fill  <<<(E / 4 + 255) / 256, 256, 0, stream>>>(e_src, e_dst, cursor, csr_src, E);
    k_bounds<<<1, 128, 0, stream>>>(batch, goff, N);

    const int aggBlocks  = (N * 32 + 255) / 256;          // 32 lanes/node
    const int gemmBlocks = (N + 63) / 64;                 // 64 rows/block

    // --- layer 1: aggregate 7-dim, then transform ---
    k_prep <<<(N * 8 + 255) / 256, 256, 0, stream>>>(x, dinv, xp, N);
    k_agg7 <<<(N * 8 + 255) / 256, 256, 0, stream>>>(xp, ax, start, csr_src, dinv, N);
    k_gemm7<<<(N + 1) / 2, 256, 0, stream>>>(ax, W1, b1, H, N);   // H = h1
    // --- layer 2 ---
    k_gemm128<<<gemmBlocks, 256, 0, stream>>>(H, W2, dinv, T, N); // T = dinv*(h1@W2)
    k_agg    <<<aggBlocks, 256, 0, stream>>>(T, H, start, csr_src, dinv, b2, 1, N);
    // --- layer 3 (no relu) ---
    k_gemm128<<<gemmBlocks, 256, 0, stream>>>(H, W3, dinv, T, N);
    k_agg    <<<aggBlocks, 256, 0, stream>>>(T, H, start, csr_src, dinv, b3, 0, N);

    // --- pool + classifier ---
    k_pool2<<<N_GRAPHS * 8, 256, 0, stream>>>(H, goff, gsum);
    k_final<<<1, 128, 0, stream>>>(gsum, goff, Wl, bl, out);
}